// Round 1
// baseline (3558.962 us; speedup 1.0000x reference)
//
#include <hip/hip_runtime.h>
#include <hip/hip_bf16.h>
#include <math.h>

// ---------------------------------------------------------------------------
// Round 1 baseline: correctness-first fp32 implementation.
//   B=1, T=2048, C=2048, H=32, G=8, HS=64, FF=5632, LEVELS=63
// Pipeline:
//   n1 = quant_relu(rmsnorm(x,w1), a1)
//   qkv = quant_relu(n1 @ attn_w^T, aq)           (2048 x 3072)
//   attention: passA (row max/sumexp), passB (recompute scores, quantize
//              softmax weights, PV) -> y (2048 x 2048)
//   x2  = x + y @ proj_w^T                         -> d_out
//   n2  = quant_relu(rmsnorm(x2,w2), a2)
//   g   = n2 @ fc1_w^T                 (raw, 2048 x 5632)
//   gu  = silu(g) * (n2 @ fc2_w^T)     (in place over g)
//   out = x2 + gu @ mlp_proj_w^T       -> d_out
// Workspace layout (floats): n(4194304) | qkv(6291456) | {y(4194304), ml(131072)}
//   reused later as g(11534336).  Total 22,020,096 floats = 84.1 MiB.
// ---------------------------------------------------------------------------

#define T_SEQ 2048
#define C_DIM 2048
#define QKV_DIM 3072
#define FF_DIM 5632

__device__ __forceinline__ float qrelu(float v, float alpha) {
  // quant_relu: round(clip(max(v,0)/alpha, 0, 1) * 63) / 63 * alpha
  float xd = fmaxf(v, 0.0f) / alpha;
  xd = fminf(xd, 1.0f);
  return rintf(xd * 63.0f) / 63.0f * alpha;   // rintf = round-half-even (matches jnp.round)
}

// ---------------------------------------------------------------------------
// RMSNorm + quant_relu.  One block per row, 256 threads x 8 elems.
// ---------------------------------------------------------------------------
__global__ __launch_bounds__(256) void rmsnorm_quant(const float* __restrict__ x,
                                                     const float* __restrict__ w,
                                                     const float* __restrict__ alpha_p,
                                                     float* __restrict__ out) {
  const int row = blockIdx.x;
  const float* xr = x + (size_t)row * C_DIM;
  const int base = threadIdx.x * 8;
  float4 v0 = *reinterpret_cast<const float4*>(xr + base);
  float4 v1 = *reinterpret_cast<const float4*>(xr + base + 4);
  float xv[8] = {v0.x, v0.y, v0.z, v0.w, v1.x, v1.y, v1.z, v1.w};
  float ss = 0.0f;
#pragma unroll
  for (int k = 0; k < 8; ++k) ss = fmaf(xv[k], xv[k], ss);
#pragma unroll
  for (int m = 1; m < 64; m <<= 1) ss += __shfl_xor(ss, m);
  __shared__ float wsum[4];
  const int lane = threadIdx.x & 63, wv = threadIdx.x >> 6;
  if (lane == 0) wsum[wv] = ss;
  __syncthreads();
  const float tot = wsum[0] + wsum[1] + wsum[2] + wsum[3];
  const float rs = 1.0f / sqrtf(tot * (1.0f / 2048.0f) + 1e-5f);
  const float alpha = *alpha_p;
  float ov[8];
#pragma unroll
  for (int k = 0; k < 8; ++k) ov[k] = qrelu((w[base + k] * xv[k]) * rs, alpha);
  float* orow = out + (size_t)row * C_DIM + base;
  *reinterpret_cast<float4*>(orow)     = make_float4(ov[0], ov[1], ov[2], ov[3]);
  *reinterpret_cast<float4*>(orow + 4) = make_float4(ov[4], ov[5], ov[6], ov[7]);
}

// ---------------------------------------------------------------------------
// Tiled fp32 GEMM:  C[m,n] = sum_k A[m,k] * B[n,k]   (both row-major, K inner)
// BM=BN=128, BK=32, 256 threads, 8x8 micro-tile.
// EPI: 0 = plain store, 1 = quant_relu(acc, *alpha_p),
//      2 = aux[idx] + acc (residual), 3 = silu(aux[idx]) * acc (gate*up)
// ---------------------------------------------------------------------------
template <int EPI>
__global__ __launch_bounds__(256) void gemm_bt(const float* __restrict__ A,
                                               const float* __restrict__ B,
                                               float* __restrict__ C,
                                               const float* __restrict__ aux,
                                               const float* __restrict__ alpha_p,
                                               int M, int N, int K) {
  __shared__ __align__(16) float As[32][132];  // [k][m], pad 132 keeps scatter-writes ~4-way
  __shared__ __align__(16) float Bs[32][132];  // [k][n]
  const int tid = threadIdx.x;
  const int tx = tid & 15, ty = tid >> 4;
  const int row0 = blockIdx.y * 128, col0 = blockIdx.x * 128;
  const int lr = tid >> 3;         // 0..31  (row within quarter-tile)
  const int lk = (tid & 7) * 4;    // k offset (float4 granularity)
  const float* Aptr = A + (size_t)(row0 + lr) * K + lk;
  const float* Bptr = B + (size_t)(col0 + lr) * K + lk;

  float acc[8][8] = {};
  for (int kt = 0; kt < K; kt += 32) {
    float4 ra[4], rb[4];
#pragma unroll
    for (int l = 0; l < 4; ++l) {
      ra[l] = *reinterpret_cast<const float4*>(Aptr + (size_t)(l * 32) * K + kt);
      rb[l] = *reinterpret_cast<const float4*>(Bptr + (size_t)(l * 32) * K + kt);
    }
    __syncthreads();
#pragma unroll
    for (int l = 0; l < 4; ++l) {
      const int r = lr + l * 32;
      As[lk + 0][r] = ra[l].x; As[lk + 1][r] = ra[l].y;
      As[lk + 2][r] = ra[l].z; As[lk + 3][r] = ra[l].w;
      Bs[lk + 0][r] = rb[l].x; Bs[lk + 1][r] = rb[l].y;
      Bs[lk + 2][r] = rb[l].z; Bs[lk + 3][r] = rb[l].w;
    }
    __syncthreads();
#pragma unroll 8
    for (int kk = 0; kk < 32; ++kk) {
      float4 a0 = *reinterpret_cast<const float4*>(&As[kk][ty * 8]);
      float4 a1 = *reinterpret_cast<const float4*>(&As[kk][ty * 8 + 4]);
      float4 b0 = *reinterpret_cast<const float4*>(&Bs[kk][tx * 8]);
      float4 b1 = *reinterpret_cast<const float4*>(&Bs[kk][tx * 8 + 4]);
      float av[8] = {a0.x, a0.y, a0.z, a0.w, a1.x, a1.y, a1.z, a1.w};
      float bv[8] = {b0.x, b0.y, b0.z, b0.w, b1.x, b1.y, b1.z, b1.w};
#pragma unroll
      for (int i = 0; i < 8; ++i)
#pragma unroll
        for (int j = 0; j < 8; ++j) acc[i][j] = fmaf(av[i], bv[j], acc[i][j]);
    }
  }

  const float alpha = (EPI == 1) ? *alpha_p : 0.0f;
#pragma unroll
  for (int i = 0; i < 8; ++i) {
    const int r = row0 + ty * 8 + i;
    const size_t base = (size_t)r * N + col0 + tx * 8;
#pragma unroll
    for (int jq = 0; jq < 2; ++jq) {
      float o[4];
#pragma unroll
      for (int j = 0; j < 4; ++j) o[j] = acc[i][jq * 4 + j];
      if constexpr (EPI == 1) {
#pragma unroll
        for (int j = 0; j < 4; ++j) o[j] = qrelu(o[j], alpha);
      } else if constexpr (EPI == 2) {
        float4 ax = *reinterpret_cast<const float4*>(&aux[base + jq * 4]);
        o[0] += ax.x; o[1] += ax.y; o[2] += ax.z; o[3] += ax.w;
      } else if constexpr (EPI == 3) {
        float4 gx = *reinterpret_cast<const float4*>(&aux[base + jq * 4]);
        float ga[4] = {gx.x, gx.y, gx.z, gx.w};
#pragma unroll
        for (int j = 0; j < 4; ++j) o[j] = (ga[j] / (1.0f + expf(-ga[j]))) * o[j];
      }
      *reinterpret_cast<float4*>(&C[base + jq * 4]) =
          make_float4(o[0], o[1], o[2], o[3]);
    }
  }
}

// ---------------------------------------------------------------------------
// Attention pass A: per (qb, h), online row max m and sumexp l over causal keys.
// Scores are computed with the IDENTICAL op sequence as pass B -> bitwise equal.
// qkv layout per row: [g][slot][64] with slot 0..3 = q heads, 4 = k, 5 = v.
// ---------------------------------------------------------------------------
__global__ __launch_bounds__(256) void attn_pass_a(const float* __restrict__ qkv,
                                                   float* __restrict__ ml) {
  const int qb = blockIdx.x, h = blockIdx.y;
  const int g = h >> 2, s = h & 3;
  const int q_col = (g * 6 + s) * 64;
  const int k_col = (g * 6 + 4) * 64;
  __shared__ __align__(16) float Qs[64][68];  // [d][row]
  __shared__ __align__(16) float Ks[64][68];  // [d][row]
  const int tid = threadIdx.x, tx = tid & 15, ty = tid >> 4;

#pragma unroll
  for (int l = 0; l < 4; ++l) {
    const int c = tid + l * 256;
    const int r = c >> 4, dq = (c & 15) * 4;
    float4 v = *reinterpret_cast<const float4*>(
        &qkv[(size_t)(qb * 64 + r) * QKV_DIM + q_col + dq]);
    Qs[dq + 0][r] = v.x; Qs[dq + 1][r] = v.y;
    Qs[dq + 2][r] = v.z; Qs[dq + 3][r] = v.w;
  }
  float m_run[4], l_run[4];
#pragma unroll
  for (int i = 0; i < 4; ++i) { m_run[i] = -INFINITY; l_run[i] = 0.0f; }

  for (int kt = 0; kt <= qb; ++kt) {
    __syncthreads();
#pragma unroll
    for (int l = 0; l < 4; ++l) {
      const int c = tid + l * 256;
      const int r = c >> 4, dq = (c & 15) * 4;
      float4 v = *reinterpret_cast<const float4*>(
          &qkv[(size_t)(kt * 64 + r) * QKV_DIM + k_col + dq]);
      Ks[dq + 0][r] = v.x; Ks[dq + 1][r] = v.y;
      Ks[dq + 2][r] = v.z; Ks[dq + 3][r] = v.w;
    }
    __syncthreads();
    float sacc[4][4] = {};
#pragma unroll 8
    for (int d = 0; d < 64; ++d) {
      float4 qv = *reinterpret_cast<const float4*>(&Qs[d][ty * 4]);
      float4 kv = *reinterpret_cast<const float4*>(&Ks[d][tx * 4]);
      float qa[4] = {qv.x, qv.y, qv.z, qv.w};
      float ka[4] = {kv.x, kv.y, kv.z, kv.w};
#pragma unroll
      for (int i = 0; i < 4; ++i)
#pragma unroll
        for (int j = 0; j < 4; ++j) sacc[i][j] = fmaf(qa[i], ka[j], sacc[i][j]);
    }
    const int rowg = qb * 64 + ty * 4;
    const int colg = kt * 64 + tx * 4;
#pragma unroll
    for (int i = 0; i < 4; ++i) {
      float sv[4];
      float mloc = -INFINITY;
#pragma unroll
      for (int j = 0; j < 4; ++j) {
        sv[j] = (colg + j <= rowg + i) ? sacc[i][j] * 0.125f : -INFINITY;
        mloc = fmaxf(mloc, sv[j]);
      }
#pragma unroll
      for (int m = 1; m < 16; m <<= 1) mloc = fmaxf(mloc, __shfl_xor(mloc, m));
      const float m_new = fmaxf(m_run[i], mloc);
      float p = 0.0f;
#pragma unroll
      for (int j = 0; j < 4; ++j) p += expf(sv[j] - m_new);  // exp(-inf)=0 for masked
#pragma unroll
      for (int m = 1; m < 16; m <<= 1) p += __shfl_xor(p, m);
      l_run[i] = l_run[i] * expf(m_run[i] - m_new) + p;
      m_run[i] = m_new;
    }
  }
  if (tx == 0) {
#pragma unroll
    for (int i = 0; i < 4; ++i) {
      const int qrow = qb * 64 + ty * 4 + i;
      ml[(size_t)(h * T_SEQ + qrow) * 2]     = m_run[i];
      ml[(size_t)(h * T_SEQ + qrow) * 2 + 1] = l_run[i];
    }
  }
}

// ---------------------------------------------------------------------------
// Attention pass B: recompute scores (bitwise same), w = exp(s-m)/l,
// quant_relu(w, alpha_sm), y += w_q @ V.
// ---------------------------------------------------------------------------
__global__ __launch_bounds__(256) void attn_pass_b(const float* __restrict__ qkv,
                                                   const float* __restrict__ ml,
                                                   float* __restrict__ y,
                                                   const float* __restrict__ alpha_p) {
  const int qb = blockIdx.x, h = blockIdx.y;
  const int g = h >> 2, s = h & 3;
  const int q_col = (g * 6 + s) * 64;
  const int k_col = (g * 6 + 4) * 64;
  const int v_col = (g * 6 + 5) * 64;
  __shared__ __align__(16) float Qs[64][68];  // [d][row]
  __shared__ __align__(16) float Ks[64][68];  // [d][row]
  __shared__ __align__(16) float Vs[64][68];  // [k][d]  (natural)
  __shared__ __align__(16) float Ws[64][72];  // [k][row] (transposed, pad 72 => clean banks)
  const int tid = threadIdx.x, tx = tid & 15, ty = tid >> 4;

#pragma unroll
  for (int l = 0; l < 4; ++l) {
    const int c = tid + l * 256;
    const int r = c >> 4, dq = (c & 15) * 4;
    float4 v = *reinterpret_cast<const float4*>(
        &qkv[(size_t)(qb * 64 + r) * QKV_DIM + q_col + dq]);
    Qs[dq + 0][r] = v.x; Qs[dq + 1][r] = v.y;
    Qs[dq + 2][r] = v.z; Qs[dq + 3][r] = v.w;
  }
  const float alpha = *alpha_p;
  float mrow[4], linv[4];
#pragma unroll
  for (int i = 0; i < 4; ++i) {
    const int qrow = qb * 64 + ty * 4 + i;
    mrow[i] = ml[(size_t)(h * T_SEQ + qrow) * 2];
    linv[i] = 1.0f / ml[(size_t)(h * T_SEQ + qrow) * 2 + 1];
  }
  float yacc[4][4] = {};

  for (int kt = 0; kt <= qb; ++kt) {
    __syncthreads();
#pragma unroll
    for (int l = 0; l < 4; ++l) {
      const int c = tid + l * 256;
      const int r = c >> 4, dq = (c & 15) * 4;
      float4 kv = *reinterpret_cast<const float4*>(
          &qkv[(size_t)(kt * 64 + r) * QKV_DIM + k_col + dq]);
      Ks[dq + 0][r] = kv.x; Ks[dq + 1][r] = kv.y;
      Ks[dq + 2][r] = kv.z; Ks[dq + 3][r] = kv.w;
      float4 vv = *reinterpret_cast<const float4*>(
          &qkv[(size_t)(kt * 64 + r) * QKV_DIM + v_col + dq]);
      *reinterpret_cast<float4*>(&Vs[r][dq]) = vv;
    }
    __syncthreads();
    float sacc[4][4] = {};
#pragma unroll 8
    for (int d = 0; d < 64; ++d) {
      float4 qv = *reinterpret_cast<const float4*>(&Qs[d][ty * 4]);
      float4 kv = *reinterpret_cast<const float4*>(&Ks[d][tx * 4]);
      float qa[4] = {qv.x, qv.y, qv.z, qv.w};
      float ka[4] = {kv.x, kv.y, kv.z, kv.w};
#pragma unroll
      for (int i = 0; i < 4; ++i)
#pragma unroll
        for (int j = 0; j < 4; ++j) sacc[i][j] = fmaf(qa[i], ka[j], sacc[i][j]);
    }
    const int rowg = qb * 64 + ty * 4;
    const int colg = kt * 64 + tx * 4;
#pragma unroll
    for (int i = 0; i < 4; ++i)
#pragma unroll
      for (int j = 0; j < 4; ++j) {
        float w = 0.0f;
        if (colg + j <= rowg + i) {
          w = expf(sacc[i][j] * 0.125f - mrow[i]) * linv[i];
          w = qrelu(w, alpha);
        }
        Ws[tx * 4 + j][ty * 4 + i] = w;
      }
    __syncthreads();
#pragma unroll 8
    for (int c = 0; c < 64; ++c) {
      float4 wv = *reinterpret_cast<const float4*>(&Ws[c][ty * 4]);
      float4 vv = *reinterpret_cast<const float4*>(&Vs[c][tx * 4]);
      float wa[4] = {wv.x, wv.y, wv.z, wv.w};
      float va[4] = {vv.x, vv.y, vv.z, vv.w};
#pragma unroll
      for (int i = 0; i < 4; ++i)
#pragma unroll
        for (int j = 0; j < 4; ++j) yacc[i][j] = fmaf(wa[i], va[j], yacc[i][j]);
    }
  }
#pragma unroll
  for (int i = 0; i < 4; ++i) {
    const int qrow = qb * 64 + ty * 4 + i;
    *reinterpret_cast<float4*>(&y[(size_t)qrow * C_DIM + h * 64 + tx * 4]) =
        make_float4(yacc[i][0], yacc[i][1], yacc[i][2], yacc[i][3]);
  }
}

// ---------------------------------------------------------------------------
extern "C" void kernel_launch(void* const* d_in, const int* in_sizes, int n_in,
                              void* d_out, int out_size, void* d_ws, size_t ws_size,
                              hipStream_t stream) {
  (void)in_sizes; (void)n_in; (void)out_size; (void)ws_size;
  const float* x      = (const float*)d_in[0];
  const float* w1     = (const float*)d_in[1];
  const float* w2     = (const float*)d_in[2];
  const float* a1     = (const float*)d_in[3];
  const float* a2     = (const float*)d_in[4];
  const float* aq     = (const float*)d_in[5];
  const float* a_sm   = (const float*)d_in[6];
  const float* attn_w = (const float*)d_in[7];
  const float* proj_w = (const float*)d_in[8];
  const float* fc1_w  = (const float*)d_in[9];
  const float* fc2_w  = (const float*)d_in[10];
  const float* mlp_w  = (const float*)d_in[11];
  float* out = (float*)d_out;

  float* ws    = (float*)d_ws;
  float* n_buf = ws;                          // 4,194,304
  float* qkv   = n_buf + 4194304;             // 6,291,456
  float* y     = qkv + 6291456;               // 4,194,304
  float* ml    = y + 4194304;                 //   131,072
  float* g_buf = y;                           // 11,534,336 (reuses y+ml after proj)
  // total 22,020,096 floats = 84.1 MiB

  // 1) n1 = quant_relu(rmsnorm(x, w1), a1)
  rmsnorm_quant<<<T_SEQ, 256, 0, stream>>>(x, w1, a1, n_buf);
  // 2) qkv = quant_relu(n1 @ attn_w^T, aq)
  gemm_bt<1><<<dim3(QKV_DIM / 128, T_SEQ / 128), 256, 0, stream>>>(
      n_buf, attn_w, qkv, nullptr, aq, T_SEQ, QKV_DIM, C_DIM);
  // 3) attention
  attn_pass_a<<<dim3(32, 32), 256, 0, stream>>>(qkv, ml);
  attn_pass_b<<<dim3(32, 32), 256, 0, stream>>>(qkv, ml, y, a_sm);
  // 4) x2 = x + y @ proj_w^T      -> d_out
  gemm_bt<2><<<dim3(C_DIM / 128, T_SEQ / 128), 256, 0, stream>>>(
      y, proj_w, out, x, nullptr, T_SEQ, C_DIM, C_DIM);
  // 5) n2 = quant_relu(rmsnorm(x2, w2), a2)
  rmsnorm_quant<<<T_SEQ, 256, 0, stream>>>(out, w2, a2, n_buf);
  // 6) g = n2 @ fc1_w^T  (raw pre-activation)
  gemm_bt<0><<<dim3(FF_DIM / 128, T_SEQ / 128), 256, 0, stream>>>(
      n_buf, fc1_w, g_buf, nullptr, nullptr, T_SEQ, FF_DIM, C_DIM);
  // 7) gu = silu(g) * (n2 @ fc2_w^T)   (in place over g)
  gemm_bt<3><<<dim3(FF_DIM / 128, T_SEQ / 128), 256, 0, stream>>>(
      n_buf, fc2_w, g_buf, g_buf, nullptr, T_SEQ, FF_DIM, C_DIM);
  // 8) out = x2 + gu @ mlp_proj_w^T    (read-modify-write d_out)
  gemm_bt<2><<<dim3(C_DIM / 128, T_SEQ / 128), 256, 0, stream>>>(
      g_buf, mlp_w, out, out, nullptr, T_SEQ, C_DIM, FF_DIM);
}

// Round 2
// 1910.201 us; speedup vs baseline: 1.8631x; 1.8631x over previous
//
#include <hip/hip_runtime.h>
#include <hip/hip_bf16.h>
#include <math.h>

// ---------------------------------------------------------------------------
// Round 2: bf16-MFMA GEMMs with exact-int activations + split-bf16 weights.
//   B=1, T=2048, C=2048, H=32, G=8, HS=64, FF=5632, LEVELS=63
// All quantized activations are ints 0..63 (exact in bf16).  Weights / generic
// fp32 activations are split w = hi + lo (bf16 each, residual ~2^-18).
//   QKV/fc1/fc2:  2-term  (A_int@B_hi + A_int@B_lo)
//   proj/mlp:     3-term  (A_hi@B_hi + A_lo@B_hi + A_hi@B_lo)
// MLP runs in two FF-halves so one reused weight-split region (24 MiB) and one
// g/gu region (23 MiB) keep total workspace at 60.5 MiB (< 84 MiB known-good).
// ---------------------------------------------------------------------------

#define T_SEQ 2048
#define C_DIM 2048
#define QKV_DIM 3072
#define FF_DIM 5632
#define FF_HALF 2816

typedef short bf16x8 __attribute__((ext_vector_type(8)));
typedef float f32x4 __attribute__((ext_vector_type(4)));
typedef unsigned short u16;

__device__ __forceinline__ u16 f2bf(float f) {
  __hip_bfloat16 h = __float2bfloat16(f);   // RNE
  return *reinterpret_cast<u16*>(&h);
}
__device__ __forceinline__ float bf2f(u16 u) {
  __hip_bfloat16 h;
  *reinterpret_cast<u16*>(&h) = u;
  return __bfloat162float(h);
}

// quant_relu -> integer level 0..63 (op order mirrors reference: /alpha, clip, *63, rint)
__device__ __forceinline__ float qint(float v, float alpha) {
  float xd = fmaxf(v, 0.0f) / alpha;
  xd = fminf(xd, 1.0f);
  return rintf(xd * 63.0f);
}

__device__ __forceinline__ void llds16(const void* g, void* l) {
  __builtin_amdgcn_global_load_lds(
      (const __attribute__((address_space(1))) unsigned int*)g,
      (__attribute__((address_space(3))) unsigned int*)l, 16, 0, 0);
}

// ---------------------------------------------------------------------------
// RMSNorm + quant -> integer levels stored as bf16 (exact).
// ---------------------------------------------------------------------------
__global__ __launch_bounds__(256) void rmsnorm_quant_int(const float* __restrict__ x,
                                                         const float* __restrict__ w,
                                                         const float* __restrict__ alpha_p,
                                                         u16* __restrict__ out) {
  const int row = blockIdx.x;
  const float* xr = x + (size_t)row * C_DIM;
  const int base = threadIdx.x * 8;
  float4 v0 = *reinterpret_cast<const float4*>(xr + base);
  float4 v1 = *reinterpret_cast<const float4*>(xr + base + 4);
  float xv[8] = {v0.x, v0.y, v0.z, v0.w, v1.x, v1.y, v1.z, v1.w};
  float ss = 0.0f;
#pragma unroll
  for (int k = 0; k < 8; ++k) ss = fmaf(xv[k], xv[k], ss);
#pragma unroll
  for (int m = 1; m < 64; m <<= 1) ss += __shfl_xor(ss, m);
  __shared__ float wsum[4];
  const int lane = threadIdx.x & 63, wv = threadIdx.x >> 6;
  if (lane == 0) wsum[wv] = ss;
  __syncthreads();
  const float tot = wsum[0] + wsum[1] + wsum[2] + wsum[3];
  const float rs = 1.0f / sqrtf(tot * (1.0f / 2048.0f) + 1e-5f);
  const float alpha = *alpha_p;
  u16 ov[8];
#pragma unroll
  for (int k = 0; k < 8; ++k) ov[k] = f2bf(qint((w[base + k] * xv[k]) * rs, alpha));
  u16* orow = out + (size_t)row * C_DIM + base;
#pragma unroll
  for (int k = 0; k < 2; ++k) {
    ushort4 u;
    u.x = ov[k * 4]; u.y = ov[k * 4 + 1]; u.z = ov[k * 4 + 2]; u.w = ov[k * 4 + 3];
    *reinterpret_cast<ushort4*>(orow + k * 4) = u;
  }
}

// ---------------------------------------------------------------------------
// fp32 -> (hi, lo) bf16 planes.  src is [rows][ld], takes cols contiguous.
// ---------------------------------------------------------------------------
__global__ __launch_bounds__(256) void conv_split(const float* __restrict__ src, int ld,
                                                  int cols,
                                                  u16* __restrict__ hi, u16* __restrict__ lo) {
  const int r = blockIdx.x;
  const int c4 = (blockIdx.y * 256 + threadIdx.x) * 4;
  if (c4 >= cols) return;
  float4 v = *reinterpret_cast<const float4*>(&src[(size_t)r * ld + c4]);
  float f[4] = {v.x, v.y, v.z, v.w};
  ushort4 h, l;
  u16 hh[4], ll[4];
#pragma unroll
  for (int j = 0; j < 4; ++j) {
    hh[j] = f2bf(f[j]);
    ll[j] = f2bf(f[j] - bf2f(hh[j]));
  }
  h.x = hh[0]; h.y = hh[1]; h.z = hh[2]; h.w = hh[3];
  l.x = ll[0]; l.y = ll[1]; l.z = ll[2]; l.w = ll[3];
  const size_t o = (size_t)r * cols + c4;
  *reinterpret_cast<ushort4*>(&hi[o]) = h;
  *reinterpret_cast<ushort4*>(&lo[o]) = l;
}

// ---------------------------------------------------------------------------
// Multi-term bf16 MFMA GEMM (m97 structure).  C[m,n] = sum_terms A_t[m,:].B_t[n,:]
// BM=BN=128, BK=32, 4 waves, each wave 64x64 via 4x4 frags of 16x16x32.
// MODE 2 (BSPLIT): terms (A0,B0)+(A0,B1).  MODE 3 (BOTH): (A0,B0)+(A1,B0)+(A0,B1).
// EPI 0: Cf = aux + acc            (fp32; aux may alias Cf)
// EPI 1: Cq = bf16(int level of quant_relu(acc*sA, alphaQ))
// EPI 2: split acc*sA -> p_hi/p_lo planes
// EPI 3: g = p_hi+p_lo; gu = silu(g) * (acc*sA); split gu -> p_hi/p_lo (in place)
// ---------------------------------------------------------------------------
template <int MODE, int EPI>
__global__ __launch_bounds__(256) void gemm_mfma(
    const u16* __restrict__ A0, const u16* __restrict__ A1,
    const u16* __restrict__ B0, const u16* __restrict__ B1,
    float* __restrict__ Cf, u16* __restrict__ Cq, const float* __restrict__ auxf,
    u16* __restrict__ p_hi, u16* __restrict__ p_lo,
    const float* __restrict__ sA_p, const float* __restrict__ aQ_p,
    int M, int N, int K) {
  constexpr int NT = (MODE == 2) ? 3 : 4;
  __shared__ __align__(16) u16 lds[NT * 4096];  // NT tiles of [128][32] bf16

  const int tid = threadIdx.x;
  // XCD-aware swizzle (all launches have nwg % 8 == 0)
  const int nwg = gridDim.x * gridDim.y;
  const int wg = blockIdx.y * gridDim.x + blockIdx.x;
  const int swz = (wg & 7) * (nwg >> 3) + (wg >> 3);
  const int bx = swz % gridDim.x, by = swz / gridDim.x;
  const int row0 = by * 128, col0 = bx * 128;

  const int w = tid >> 6, lane = tid & 63;
  const int wr = w >> 1, wc = w & 1;
  const int fr = lane & 15, ko = (lane >> 4) * 8;

  // staging geometry: chunk c = w*128 + lane (+64), row = c>>2, slot byte16 = c&3
  const int c0 = w * 128 + lane;
  const int r_a = c0 >> 2;          // issue-0 row; issue-1 row = r_a + 16
  const int s_a = (c0 & 3) * 8;     // element offset of 16B slot

  u16* tA0 = lds;
  u16* tX1 = lds + 4096;                      // MODE2: B0 | MODE3: A1
  u16* tX2 = lds + 8192;                      // MODE2: B1 | MODE3: B0
  u16* tX3 = (MODE == 3) ? lds + 12288 : lds; // MODE3: B1

  f32x4 acc[4][4];
  const f32x4 zero = {0.f, 0.f, 0.f, 0.f};
#pragma unroll
  for (int m = 0; m < 4; ++m)
#pragma unroll
    for (int n = 0; n < 4; ++n) acc[m][n] = zero;

  for (int kt = 0; kt < K; kt += 32) {
    __syncthreads();
    {
      const u16* g0 = A0 + (size_t)(row0 + r_a) * K + kt + s_a;
      const u16* g1 = A0 + (size_t)(row0 + r_a + 16) * K + kt + s_a;
      llds16(g0, tA0 + (w * 128) * 8);
      llds16(g1, tA0 + (w * 128 + 64) * 8);
    }
    if constexpr (MODE == 3) {
      const u16* g0 = A1 + (size_t)(row0 + r_a) * K + kt + s_a;
      const u16* g1 = A1 + (size_t)(row0 + r_a + 16) * K + kt + s_a;
      llds16(g0, tX1 + (w * 128) * 8);
      llds16(g1, tX1 + (w * 128 + 64) * 8);
    }
    {
      u16* dst = (MODE == 2) ? tX1 : tX2;
      const u16* g0 = B0 + (size_t)(col0 + r_a) * K + kt + s_a;
      const u16* g1 = B0 + (size_t)(col0 + r_a + 16) * K + kt + s_a;
      llds16(g0, dst + (w * 128) * 8);
      llds16(g1, dst + (w * 128 + 64) * 8);
    }
    {
      u16* dst = (MODE == 2) ? tX2 : tX3;
      const u16* g0 = B1 + (size_t)(col0 + r_a) * K + kt + s_a;
      const u16* g1 = B1 + (size_t)(col0 + r_a + 16) * K + kt + s_a;
      llds16(g0, dst + (w * 128) * 8);
      llds16(g1, dst + (w * 128 + 64) * 8);
    }
    __syncthreads();

    bf16x8 a0f[4], bhf[4], blf[4];
    const u16* Bhi = (MODE == 2) ? tX1 : tX2;
    const u16* Blo = (MODE == 2) ? tX2 : tX3;
#pragma unroll
    for (int m = 0; m < 4; ++m)
      a0f[m] = *reinterpret_cast<const bf16x8*>(&tA0[(wr * 64 + m * 16 + fr) * 32 + ko]);
#pragma unroll
    for (int n = 0; n < 4; ++n) {
      bhf[n] = *reinterpret_cast<const bf16x8*>(&Bhi[(wc * 64 + n * 16 + fr) * 32 + ko]);
      blf[n] = *reinterpret_cast<const bf16x8*>(&Blo[(wc * 64 + n * 16 + fr) * 32 + ko]);
    }
    if constexpr (MODE == 2) {
#pragma unroll
      for (int m = 0; m < 4; ++m)
#pragma unroll
        for (int n = 0; n < 4; ++n) {
          acc[m][n] = __builtin_amdgcn_mfma_f32_16x16x32_bf16(a0f[m], bhf[n], acc[m][n], 0, 0, 0);
          acc[m][n] = __builtin_amdgcn_mfma_f32_16x16x32_bf16(a0f[m], blf[n], acc[m][n], 0, 0, 0);
        }
    } else {
      bf16x8 a1f[4];
#pragma unroll
      for (int m = 0; m < 4; ++m)
        a1f[m] = *reinterpret_cast<const bf16x8*>(&tX1[(wr * 64 + m * 16 + fr) * 32 + ko]);
#pragma unroll
      for (int m = 0; m < 4; ++m)
#pragma unroll
        for (int n = 0; n < 4; ++n) {
          acc[m][n] = __builtin_amdgcn_mfma_f32_16x16x32_bf16(a0f[m], bhf[n], acc[m][n], 0, 0, 0);
          acc[m][n] = __builtin_amdgcn_mfma_f32_16x16x32_bf16(a1f[m], bhf[n], acc[m][n], 0, 0, 0);
          acc[m][n] = __builtin_amdgcn_mfma_f32_16x16x32_bf16(a0f[m], blf[n], acc[m][n], 0, 0, 0);
        }
    }
  }

  // epilogue.  C/D layout: col = lane&15, row = (lane>>4)*4 + reg
  float sA = 1.0f, aQ = 1.0f;
  if constexpr (EPI == 1) { sA = (*sA_p) * (1.0f / 63.0f); aQ = *aQ_p; }
  if constexpr (EPI == 2 || EPI == 3) { sA = (*sA_p) * (1.0f / 63.0f); }
#pragma unroll
  for (int m = 0; m < 4; ++m)
#pragma unroll
    for (int n = 0; n < 4; ++n) {
      const int gcol = col0 + wc * 64 + n * 16 + fr;
#pragma unroll
      for (int j = 0; j < 4; ++j) {
        const int grow = row0 + wr * 64 + m * 16 + (lane >> 4) * 4 + j;
        const size_t idx = (size_t)grow * N + gcol;
        const float v = acc[m][n][j];
        if constexpr (EPI == 0) {
          Cf[idx] = auxf[idx] + v;
        } else if constexpr (EPI == 1) {
          float t = v * sA;
          float xd = fminf(fmaxf(t, 0.0f) / aQ, 1.0f);
          Cq[idx] = f2bf(rintf(xd * 63.0f));
        } else if constexpr (EPI == 2) {
          float t = v * sA;
          u16 h = f2bf(t);
          p_hi[idx] = h;
          p_lo[idx] = f2bf(t - bf2f(h));
        } else if constexpr (EPI == 3) {
          float gg = bf2f(p_hi[idx]) + bf2f(p_lo[idx]);
          float u = v * sA;
          float gu = (gg / (1.0f + expf(-gg))) * u;
          u16 h = f2bf(gu);
          p_hi[idx] = h;
          p_lo[idx] = f2bf(gu - bf2f(h));
        }
      }
    }
}

// ---------------------------------------------------------------------------
// Attention pass A (online max/sumexp).  qkv holds exact int levels as bf16;
// scores = (int dot) * scale, scale = (alpha_q/63)^2 / 8.  Identical op order
// in pass B guarantees bitwise-equal score recompute.
// ---------------------------------------------------------------------------
__global__ __launch_bounds__(256) void attn_pass_a(const u16* __restrict__ qkv,
                                                   float* __restrict__ ml,
                                                   const float* __restrict__ aq_p) {
  const int qb = blockIdx.x, h = blockIdx.y;
  const int g = h >> 2, s = h & 3;
  const int q_col = (g * 6 + s) * 64;
  const int k_col = (g * 6 + 4) * 64;
  __shared__ __align__(16) float Qs[64][68];
  __shared__ __align__(16) float Ks[64][68];
  const int tid = threadIdx.x, tx = tid & 15, ty = tid >> 4;
  const float sq = (*aq_p) * (1.0f / 63.0f);
  const float scale = sq * sq * 0.125f;

#pragma unroll
  for (int l = 0; l < 2; ++l) {
    const int c = tid + l * 256;
    const int r = c >> 3, d8 = (c & 7) * 8;
    bf16x8 v = *reinterpret_cast<const bf16x8*>(
        &qkv[(size_t)(qb * 64 + r) * QKV_DIM + q_col + d8]);
#pragma unroll
    for (int j = 0; j < 8; ++j) Qs[d8 + j][r] = bf2f((u16)v[j]);
  }
  float m_run[4], l_run[4];
#pragma unroll
  for (int i = 0; i < 4; ++i) { m_run[i] = -INFINITY; l_run[i] = 0.0f; }

  for (int kt = 0; kt <= qb; ++kt) {
    __syncthreads();
#pragma unroll
    for (int l = 0; l < 2; ++l) {
      const int c = tid + l * 256;
      const int r = c >> 3, d8 = (c & 7) * 8;
      bf16x8 v = *reinterpret_cast<const bf16x8*>(
          &qkv[(size_t)(kt * 64 + r) * QKV_DIM + k_col + d8]);
#pragma unroll
      for (int j = 0; j < 8; ++j) Ks[d8 + j][r] = bf2f((u16)v[j]);
    }
    __syncthreads();
    float sacc[4][4] = {};
#pragma unroll 8
    for (int d = 0; d < 64; ++d) {
      float4 qv = *reinterpret_cast<const float4*>(&Qs[d][ty * 4]);
      float4 kv = *reinterpret_cast<const float4*>(&Ks[d][tx * 4]);
      float qa[4] = {qv.x, qv.y, qv.z, qv.w};
      float ka[4] = {kv.x, kv.y, kv.z, kv.w};
#pragma unroll
      for (int i = 0; i < 4; ++i)
#pragma unroll
        for (int j = 0; j < 4; ++j) sacc[i][j] = fmaf(qa[i], ka[j], sacc[i][j]);
    }
    const int rowg = qb * 64 + ty * 4;
    const int colg = kt * 64 + tx * 4;
#pragma unroll
    for (int i = 0; i < 4; ++i) {
      float sv[4];
      float mloc = -INFINITY;
#pragma unroll
      for (int j = 0; j < 4; ++j) {
        sv[j] = (colg + j <= rowg + i) ? sacc[i][j] * scale : -INFINITY;
        mloc = fmaxf(mloc, sv[j]);
      }
#pragma unroll
      for (int m = 1; m < 16; m <<= 1) mloc = fmaxf(mloc, __shfl_xor(mloc, m));
      const float m_new = fmaxf(m_run[i], mloc);
      float p = 0.0f;
#pragma unroll
      for (int j = 0; j < 4; ++j) p += expf(sv[j] - m_new);
#pragma unroll
      for (int m = 1; m < 16; m <<= 1) p += __shfl_xor(p, m);
      l_run[i] = l_run[i] * expf(m_run[i] - m_new) + p;
      m_run[i] = m_new;
    }
  }
  if (tx == 0) {
#pragma unroll
    for (int i = 0; i < 4; ++i) {
      const int qrow = qb * 64 + ty * 4 + i;
      ml[(size_t)(h * T_SEQ + qrow) * 2]     = m_run[i];
      ml[(size_t)(h * T_SEQ + qrow) * 2 + 1] = l_run[i];
    }
  }
}

// ---------------------------------------------------------------------------
// Attention pass B: recompute scores, w_int = quant level of softmax weight,
// y = (w_int @ v_int) * scale_y, write y as split hi/lo planes.
// ---------------------------------------------------------------------------
__global__ __launch_bounds__(256) void attn_pass_b(const u16* __restrict__ qkv,
                                                   const float* __restrict__ ml,
                                                   u16* __restrict__ y_hi,
                                                   u16* __restrict__ y_lo,
                                                   const float* __restrict__ aq_p,
                                                   const float* __restrict__ asm_p) {
  const int qb = blockIdx.x, h = blockIdx.y;
  const int g = h >> 2, s = h & 3;
  const int q_col = (g * 6 + s) * 64;
  const int k_col = (g * 6 + 4) * 64;
  const int v_col = (g * 6 + 5) * 64;
  __shared__ __align__(16) float Qs[64][68];
  __shared__ __align__(16) float Ks[64][68];
  __shared__ __align__(16) float Vs[64][68];
  __shared__ __align__(16) float Ws[64][72];
  const int tid = threadIdx.x, tx = tid & 15, ty = tid >> 4;
  const float sq = (*aq_p) * (1.0f / 63.0f);
  const float scale = sq * sq * 0.125f;
  const float alpha_sm = *asm_p;
  const float scale_y = (alpha_sm * (1.0f / 63.0f)) * sq;

#pragma unroll
  for (int l = 0; l < 2; ++l) {
    const int c = tid + l * 256;
    const int r = c >> 3, d8 = (c & 7) * 8;
    bf16x8 v = *reinterpret_cast<const bf16x8*>(
        &qkv[(size_t)(qb * 64 + r) * QKV_DIM + q_col + d8]);
#pragma unroll
    for (int j = 0; j < 8; ++j) Qs[d8 + j][r] = bf2f((u16)v[j]);
  }
  float mrow[4], linv[4];
#pragma unroll
  for (int i = 0; i < 4; ++i) {
    const int qrow = qb * 64 + ty * 4 + i;
    mrow[i] = ml[(size_t)(h * T_SEQ + qrow) * 2];
    linv[i] = 1.0f / ml[(size_t)(h * T_SEQ + qrow) * 2 + 1];
  }
  float yacc[4][4] = {};

  for (int kt = 0; kt <= qb; ++kt) {
    __syncthreads();
#pragma unroll
    for (int l = 0; l < 2; ++l) {
      const int c = tid + l * 256;
      const int r = c >> 3, d8 = (c & 7) * 8;
      bf16x8 kv = *reinterpret_cast<const bf16x8*>(
          &qkv[(size_t)(kt * 64 + r) * QKV_DIM + k_col + d8]);
#pragma unroll
      for (int j = 0; j < 8; ++j) Ks[d8 + j][r] = bf2f((u16)kv[j]);
      bf16x8 vv = *reinterpret_cast<const bf16x8*>(
          &qkv[(size_t)(kt * 64 + r) * QKV_DIM + v_col + d8]);
      float vf[8];
#pragma unroll
      for (int j = 0; j < 8; ++j) vf[j] = bf2f((u16)vv[j]);
      *reinterpret_cast<float4*>(&Vs[r][d8])     = make_float4(vf[0], vf[1], vf[2], vf[3]);
      *reinterpret_cast<float4*>(&Vs[r][d8 + 4]) = make_float4(vf[4], vf[5], vf[6], vf[7]);
    }
    __syncthreads();
    float sacc[4][4] = {};
#pragma unroll 8
    for (int d = 0; d < 64; ++d) {
      float4 qv = *reinterpret_cast<const float4*>(&Qs[d][ty * 4]);
      float4 kv = *reinterpret_cast<const float4*>(&Ks[d][tx * 4]);
      float qa[4] = {qv.x, qv.y, qv.z, qv.w};
      float ka[4] = {kv.x, kv.y, kv.z, kv.w};
#pragma unroll
      for (int i = 0; i < 4; ++i)
#pragma unroll
        for (int j = 0; j < 4; ++j) sacc[i][j] = fmaf(qa[i], ka[j], sacc[i][j]);
    }
    const int rowg = qb * 64 + ty * 4;
    const int colg = kt * 64 + tx * 4;
#pragma unroll
    for (int i = 0; i < 4; ++i)
#pragma unroll
      for (int j = 0; j < 4; ++j) {
        float wq = 0.0f;
        if (colg + j <= rowg + i) {
          float sv = sacc[i][j] * scale;
          float wv = expf(sv - mrow[i]) * linv[i];
          float xd = fminf(wv / alpha_sm, 1.0f);
          wq = rintf(xd * 63.0f);
        }
        Ws[tx * 4 + j][ty * 4 + i] = wq;
      }
    __syncthreads();
#pragma unroll 8
    for (int c = 0; c < 64; ++c) {
      float4 wv = *reinterpret_cast<const float4*>(&Ws[c][ty * 4]);
      float4 vv = *reinterpret_cast<const float4*>(&Vs[c][tx * 4]);
      float wa[4] = {wv.x, wv.y, wv.z, wv.w};
      float va[4] = {vv.x, vv.y, vv.z, vv.w};
#pragma unroll
      for (int i = 0; i < 4; ++i)
#pragma unroll
        for (int j = 0; j < 4; ++j) yacc[i][j] = fmaf(wa[i], va[j], yacc[i][j]);
    }
  }
#pragma unroll
  for (int i = 0; i < 4; ++i) {
    const int qrow = qb * 64 + ty * 4 + i;
    const size_t base = (size_t)qrow * C_DIM + h * 64 + tx * 4;
#pragma unroll
    for (int j = 0; j < 4; ++j) {
      float yv = yacc[i][j] * scale_y;
      u16 hh = f2bf(yv);
      y_hi[base + j] = hh;
      y_lo[base + j] = f2bf(yv - bf2f(hh));
    }
  }
}

// ---------------------------------------------------------------------------
extern "C" void kernel_launch(void* const* d_in, const int* in_sizes, int n_in,
                              void* d_out, int out_size, void* d_ws, size_t ws_size,
                              hipStream_t stream) {
  (void)in_sizes; (void)n_in; (void)out_size; (void)ws_size;
  const float* x      = (const float*)d_in[0];
  const float* w1     = (const float*)d_in[1];
  const float* w2     = (const float*)d_in[2];
  const float* a1     = (const float*)d_in[3];
  const float* a2     = (const float*)d_in[4];
  const float* aq     = (const float*)d_in[5];
  const float* a_sm   = (const float*)d_in[6];
  const float* attn_w = (const float*)d_in[7];
  const float* proj_w = (const float*)d_in[8];
  const float* fc1_w  = (const float*)d_in[9];
  const float* fc2_w  = (const float*)d_in[10];
  const float* mlp_w  = (const float*)d_in[11];
  float* out = (float*)d_out;

  // Workspace regions (bytes):
  //   [0, 25165824)            W: current weight split (hi plane | lo plane)
  //   [25165824, 33554432)     nb: n1/n2 integer levels (bf16)
  //   [33554432, 63438848)     A: qkv_i | y_hi | y_lo | ml   -> later ghi | glo
  char* ws = (char*)d_ws;
  u16* Whi   = (u16*)ws;
  u16* nb    = (u16*)(ws + 25165824);
  char* A    = ws + 33554432;
  u16* qkv_i = (u16*)A;
  u16* y_hi  = (u16*)(A + 12582912);
  u16* y_lo  = (u16*)(A + 20971520);
  float* ml  = (float*)(A + 29360128);
  u16* ghi   = (u16*)A;
  u16* glo   = (u16*)(A + 11534336);

  // 1) n1 levels
  rmsnorm_quant_int<<<T_SEQ, 256, 0, stream>>>(x, w1, a1, nb);
  // 2) qkv = quant levels of (n1 @ attn_w^T)
  conv_split<<<dim3(QKV_DIM, 2), 256, 0, stream>>>(attn_w, C_DIM, C_DIM,
                                                   Whi, Whi + (size_t)QKV_DIM * C_DIM);
  gemm_mfma<2, 1><<<dim3(QKV_DIM / 128, T_SEQ / 128), 256, 0, stream>>>(
      nb, nullptr, Whi, Whi + (size_t)QKV_DIM * C_DIM, nullptr, qkv_i, nullptr,
      nullptr, nullptr, a1, aq, T_SEQ, QKV_DIM, C_DIM);
  // 3) attention
  attn_pass_a<<<dim3(32, 32), 256, 0, stream>>>(qkv_i, ml, aq);
  attn_pass_b<<<dim3(32, 32), 256, 0, stream>>>(qkv_i, ml, y_hi, y_lo, aq, a_sm);
  // 4) x2 = x + y @ proj_w^T
  conv_split<<<dim3(C_DIM, 2), 256, 0, stream>>>(proj_w, C_DIM, C_DIM,
                                                 Whi, Whi + (size_t)C_DIM * C_DIM);
  gemm_mfma<3, 0><<<dim3(C_DIM / 128, T_SEQ / 128), 256, 0, stream>>>(
      y_hi, y_lo, Whi, Whi + (size_t)C_DIM * C_DIM, out, nullptr, x,
      nullptr, nullptr, nullptr, nullptr, T_SEQ, C_DIM, C_DIM);
  // 5) n2 levels
  rmsnorm_quant_int<<<T_SEQ, 256, 0, stream>>>(out, w2, a2, nb);
  // 6-8) MLP in two FF halves
  for (int h = 0; h < 2; ++h) {
    const float* fc1h = fc1_w + (size_t)h * FF_HALF * C_DIM;
    const float* fc2h = fc2_w + (size_t)h * FF_HALF * C_DIM;
    const float* mlph = mlp_w + (size_t)h * FF_HALF;
    // g = n2 @ fc1h^T  (split planes)
    conv_split<<<dim3(FF_HALF, 2), 256, 0, stream>>>(fc1h, C_DIM, C_DIM,
                                                     Whi, Whi + (size_t)FF_HALF * C_DIM);
    gemm_mfma<2, 2><<<dim3(FF_HALF / 128, T_SEQ / 128), 256, 0, stream>>>(
        nb, nullptr, Whi, Whi + (size_t)FF_HALF * C_DIM, nullptr, nullptr, nullptr,
        ghi, glo, a2, nullptr, T_SEQ, FF_HALF, C_DIM);
    // gu = silu(g) * (n2 @ fc2h^T)  (split planes, in place)
    conv_split<<<dim3(FF_HALF, 2), 256, 0, stream>>>(fc2h, C_DIM, C_DIM,
                                                     Whi, Whi + (size_t)FF_HALF * C_DIM);
    gemm_mfma<2, 3><<<dim3(FF_HALF / 128, T_SEQ / 128), 256, 0, stream>>>(
        nb, nullptr, Whi, Whi + (size_t)FF_HALF * C_DIM, nullptr, nullptr, nullptr,
        ghi, glo, a2, nullptr, T_SEQ, FF_HALF, C_DIM);
    // out += gu @ mlph^T   (mlp_w is [C][FF]; take col slice, ld = FF)
    conv_split<<<dim3(C_DIM, 3), 256, 0, stream>>>(mlph, FF_DIM, FF_HALF,
                                                   Whi, Whi + (size_t)C_DIM * FF_HALF);
    gemm_mfma<3, 0><<<dim3(C_DIM / 128, T_SEQ / 128), 256, 0, stream>>>(
        ghi, glo, Whi, Whi + (size_t)C_DIM * FF_HALF, out, nullptr, out,
        nullptr, nullptr, nullptr, nullptr, T_SEQ, C_DIM, FF_HALF);
  }
}

// Round 4
// 1184.093 us; speedup vs baseline: 3.0056x; 1.6132x over previous
//
#include <hip/hip_runtime.h>
#include <hip/hip_bf16.h>
#include <math.h>

// ---------------------------------------------------------------------------
// Round 3 (resubmit; round-3 bench never ran - GPU acquisition timeout).
// MFMA everywhere.  GEMMs unchanged from round 2 (verified).
// NEW: fused MFMA attention (swapped QK^T, exact int bf16 MFMA, two-phase
// online stats + bitwise-identical recompute, PV as O^T = V^T @ W^T with
// globally pre-transposed V).  All LDS tiles XOR-swizzled ((row&7)<<4) with
// pre-swizzled global_load_lds sources.
//   B=1, T=2048, C=2048, H=32, G=8, HS=64, FF=5632, LEVELS=63
// ---------------------------------------------------------------------------

#define T_SEQ 2048
#define C_DIM 2048
#define QKV_DIM 3072
#define FF_DIM 5632
#define FF_HALF 2816

typedef short bf16x8 __attribute__((ext_vector_type(8)));
typedef float f32x4 __attribute__((ext_vector_type(4)));
typedef unsigned short u16;
typedef unsigned int u32;

__device__ __forceinline__ u16 f2bf(float f) {
  __hip_bfloat16 h = __float2bfloat16(f);   // RNE
  return *reinterpret_cast<u16*>(&h);
}
__device__ __forceinline__ float bf2f(u16 u) {
  __hip_bfloat16 h;
  *reinterpret_cast<u16*>(&h) = u;
  return __bfloat162float(h);
}

__device__ __forceinline__ float qint(float v, float alpha) {
  float xd = fmaxf(v, 0.0f) / alpha;
  xd = fminf(xd, 1.0f);
  return rintf(xd * 63.0f);
}

__device__ __forceinline__ void llds16(const void* g, void* l) {
  __builtin_amdgcn_global_load_lds(
      (const __attribute__((address_space(1))) unsigned int*)g,
      (__attribute__((address_space(3))) unsigned int*)l, 16, 0, 0);
}

// ---------------------------------------------------------------------------
// RMSNorm + quant -> integer levels stored as bf16 (exact).
// ---------------------------------------------------------------------------
__global__ __launch_bounds__(256) void rmsnorm_quant_int(const float* __restrict__ x,
                                                         const float* __restrict__ w,
                                                         const float* __restrict__ alpha_p,
                                                         u16* __restrict__ out) {
  const int row = blockIdx.x;
  const float* xr = x + (size_t)row * C_DIM;
  const int base = threadIdx.x * 8;
  float4 v0 = *reinterpret_cast<const float4*>(xr + base);
  float4 v1 = *reinterpret_cast<const float4*>(xr + base + 4);
  float xv[8] = {v0.x, v0.y, v0.z, v0.w, v1.x, v1.y, v1.z, v1.w};
  float ss = 0.0f;
#pragma unroll
  for (int k = 0; k < 8; ++k) ss = fmaf(xv[k], xv[k], ss);
#pragma unroll
  for (int m = 1; m < 64; m <<= 1) ss += __shfl_xor(ss, m);
  __shared__ float wsum[4];
  const int lane = threadIdx.x & 63, wv = threadIdx.x >> 6;
  if (lane == 0) wsum[wv] = ss;
  __syncthreads();
  const float tot = wsum[0] + wsum[1] + wsum[2] + wsum[3];
  const float rs = 1.0f / sqrtf(tot * (1.0f / 2048.0f) + 1e-5f);
  const float alpha = *alpha_p;
  u16 ov[8];
#pragma unroll
  for (int k = 0; k < 8; ++k) ov[k] = f2bf(qint((w[base + k] * xv[k]) * rs, alpha));
  u16* orow = out + (size_t)row * C_DIM + base;
#pragma unroll
  for (int k = 0; k < 2; ++k) {
    ushort4 u;
    u.x = ov[k * 4]; u.y = ov[k * 4 + 1]; u.z = ov[k * 4 + 2]; u.w = ov[k * 4 + 3];
    *reinterpret_cast<ushort4*>(orow + k * 4) = u;
  }
}

// ---------------------------------------------------------------------------
// fp32 -> (hi, lo) bf16 planes.
// ---------------------------------------------------------------------------
__global__ __launch_bounds__(256) void conv_split(const float* __restrict__ src, int ld,
                                                  int cols,
                                                  u16* __restrict__ hi, u16* __restrict__ lo) {
  const int r = blockIdx.x;
  const int c4 = (blockIdx.y * 256 + threadIdx.x) * 4;
  if (c4 >= cols) return;
  float4 v = *reinterpret_cast<const float4*>(&src[(size_t)r * ld + c4]);
  float f[4] = {v.x, v.y, v.z, v.w};
  ushort4 h, l;
  u16 hh[4], ll[4];
#pragma unroll
  for (int j = 0; j < 4; ++j) {
    hh[j] = f2bf(f[j]);
    ll[j] = f2bf(f[j] - bf2f(hh[j]));
  }
  h.x = hh[0]; h.y = hh[1]; h.z = hh[2]; h.w = hh[3];
  l.x = ll[0]; l.y = ll[1]; l.z = ll[2]; l.w = ll[3];
  const size_t o = (size_t)r * cols + c4;
  *reinterpret_cast<ushort4*>(&hi[o]) = h;
  *reinterpret_cast<ushort4*>(&lo[o]) = l;
}

// ---------------------------------------------------------------------------
// Multi-term bf16 MFMA GEMM (unchanged from round 2, verified).
// ---------------------------------------------------------------------------
template <int MODE, int EPI>
__global__ __launch_bounds__(256) void gemm_mfma(
    const u16* __restrict__ A0, const u16* __restrict__ A1,
    const u16* __restrict__ B0, const u16* __restrict__ B1,
    float* __restrict__ Cf, u16* __restrict__ Cq, const float* __restrict__ auxf,
    u16* __restrict__ p_hi, u16* __restrict__ p_lo,
    const float* __restrict__ sA_p, const float* __restrict__ aQ_p,
    int M, int N, int K) {
  constexpr int NT = (MODE == 2) ? 3 : 4;
  __shared__ __align__(16) u16 lds[NT * 4096];

  const int tid = threadIdx.x;
  const int nwg = gridDim.x * gridDim.y;
  const int wg = blockIdx.y * gridDim.x + blockIdx.x;
  const int swz = (wg & 7) * (nwg >> 3) + (wg >> 3);
  const int bx = swz % gridDim.x, by = swz / gridDim.x;
  const int row0 = by * 128, col0 = bx * 128;

  const int w = tid >> 6, lane = tid & 63;
  const int wr = w >> 1, wc = w & 1;
  const int fr = lane & 15, ko = (lane >> 4) * 8;

  const int c0 = w * 128 + lane;
  const int r_a = c0 >> 2;
  const int s_a = (c0 & 3) * 8;

  u16* tA0 = lds;
  u16* tX1 = lds + 4096;
  u16* tX2 = lds + 8192;
  u16* tX3 = (MODE == 3) ? lds + 12288 : lds;

  f32x4 acc[4][4];
  const f32x4 zero = {0.f, 0.f, 0.f, 0.f};
#pragma unroll
  for (int m = 0; m < 4; ++m)
#pragma unroll
    for (int n = 0; n < 4; ++n) acc[m][n] = zero;

  for (int kt = 0; kt < K; kt += 32) {
    __syncthreads();
    {
      const u16* g0 = A0 + (size_t)(row0 + r_a) * K + kt + s_a;
      const u16* g1 = A0 + (size_t)(row0 + r_a + 16) * K + kt + s_a;
      llds16(g0, tA0 + (w * 128) * 8);
      llds16(g1, tA0 + (w * 128 + 64) * 8);
    }
    if constexpr (MODE == 3) {
      const u16* g0 = A1 + (size_t)(row0 + r_a) * K + kt + s_a;
      const u16* g1 = A1 + (size_t)(row0 + r_a + 16) * K + kt + s_a;
      llds16(g0, tX1 + (w * 128) * 8);
      llds16(g1, tX1 + (w * 128 + 64) * 8);
    }
    {
      u16* dst = (MODE == 2) ? tX1 : tX2;
      const u16* g0 = B0 + (size_t)(col0 + r_a) * K + kt + s_a;
      const u16* g1 = B0 + (size_t)(col0 + r_a + 16) * K + kt + s_a;
      llds16(g0, dst + (w * 128) * 8);
      llds16(g1, dst + (w * 128 + 64) * 8);
    }
    {
      u16* dst = (MODE == 2) ? tX2 : tX3;
      const u16* g0 = B1 + (size_t)(col0 + r_a) * K + kt + s_a;
      const u16* g1 = B1 + (size_t)(col0 + r_a + 16) * K + kt + s_a;
      llds16(g0, dst + (w * 128) * 8);
      llds16(g1, dst + (w * 128 + 64) * 8);
    }
    __syncthreads();

    bf16x8 a0f[4], bhf[4], blf[4];
    const u16* Bhi = (MODE == 2) ? tX1 : tX2;
    const u16* Blo = (MODE == 2) ? tX2 : tX3;
#pragma unroll
    for (int m = 0; m < 4; ++m)
      a0f[m] = *reinterpret_cast<const bf16x8*>(&tA0[(wr * 64 + m * 16 + fr) * 32 + ko]);
#pragma unroll
    for (int n = 0; n < 4; ++n) {
      bhf[n] = *reinterpret_cast<const bf16x8*>(&Bhi[(wc * 64 + n * 16 + fr) * 32 + ko]);
      blf[n] = *reinterpret_cast<const bf16x8*>(&Blo[(wc * 64 + n * 16 + fr) * 32 + ko]);
    }
    if constexpr (MODE == 2) {
#pragma unroll
      for (int m = 0; m < 4; ++m)
#pragma unroll
        for (int n = 0; n < 4; ++n) {
          acc[m][n] = __builtin_amdgcn_mfma_f32_16x16x32_bf16(a0f[m], bhf[n], acc[m][n], 0, 0, 0);
          acc[m][n] = __builtin_amdgcn_mfma_f32_16x16x32_bf16(a0f[m], blf[n], acc[m][n], 0, 0, 0);
        }
    } else {
      bf16x8 a1f[4];
#pragma unroll
      for (int m = 0; m < 4; ++m)
        a1f[m] = *reinterpret_cast<const bf16x8*>(&tX1[(wr * 64 + m * 16 + fr) * 32 + ko]);
#pragma unroll
      for (int m = 0; m < 4; ++m)
#pragma unroll
        for (int n = 0; n < 4; ++n) {
          acc[m][n] = __builtin_amdgcn_mfma_f32_16x16x32_bf16(a0f[m], bhf[n], acc[m][n], 0, 0, 0);
          acc[m][n] = __builtin_amdgcn_mfma_f32_16x16x32_bf16(a1f[m], bhf[n], acc[m][n], 0, 0, 0);
          acc[m][n] = __builtin_amdgcn_mfma_f32_16x16x32_bf16(a0f[m], blf[n], acc[m][n], 0, 0, 0);
        }
    }
  }

  float sA = 1.0f, aQ = 1.0f;
  if constexpr (EPI == 1) { sA = (*sA_p) * (1.0f / 63.0f); aQ = *aQ_p; }
  if constexpr (EPI == 2 || EPI == 3) { sA = (*sA_p) * (1.0f / 63.0f); }
#pragma unroll
  for (int m = 0; m < 4; ++m)
#pragma unroll
    for (int n = 0; n < 4; ++n) {
      const int gcol = col0 + wc * 64 + n * 16 + fr;
#pragma unroll
      for (int j = 0; j < 4; ++j) {
        const int grow = row0 + wr * 64 + m * 16 + (lane >> 4) * 4 + j;
        const size_t idx = (size_t)grow * N + gcol;
        const float v = acc[m][n][j];
        if constexpr (EPI == 0) {
          Cf[idx] = auxf[idx] + v;
        } else if constexpr (EPI == 1) {
          float t = v * sA;
          float xd = fminf(fmaxf(t, 0.0f) / aQ, 1.0f);
          Cq[idx] = f2bf(rintf(xd * 63.0f));
        } else if constexpr (EPI == 2) {
          float t = v * sA;
          u16 h = f2bf(t);
          p_hi[idx] = h;
          p_lo[idx] = f2bf(t - bf2f(h));
        } else if constexpr (EPI == 3) {
          float gg = bf2f(p_hi[idx]) + bf2f(p_lo[idx]);
          float u = v * sA;
          float gu = (gg / (1.0f + expf(-gg))) * u;
          u16 h = f2bf(gu);
          p_hi[idx] = h;
          p_lo[idx] = f2bf(gu - bf2f(h));
        }
      }
    }
}

// ---------------------------------------------------------------------------
// V pre-transpose: vt[g][hs][t] = qkv[t][(g*6+5)*64 + hs]  (bf16 levels)
// ---------------------------------------------------------------------------
__global__ __launch_bounds__(256) void v_transpose(const u16* __restrict__ qkv,
                                                   u16* __restrict__ vt) {
  const int tb = blockIdx.x, g = blockIdx.y;
  const int vcol = (g * 6 + 5) * 64;
  __shared__ u16 t[64][72];
  const int tid = threadIdx.x;
#pragma unroll
  for (int i = 0; i < 2; ++i) {
    const int ch = i * 256 + tid;
    const int row = ch >> 3, c8 = (ch & 7) * 8;
    bf16x8 v = *reinterpret_cast<const bf16x8*>(
        qkv + (size_t)(tb * 64 + row) * QKV_DIM + vcol + c8);
#pragma unroll
    for (int j = 0; j < 8; ++j) t[c8 + j][row] = (u16)v[j];
  }
  __syncthreads();
#pragma unroll
  for (int i = 0; i < 2; ++i) {
    const int ch = i * 256 + tid;
    const int hs = ch >> 3, t8 = (ch & 7) * 8;
    ushort4 a, b;
    a.x = t[hs][t8];     a.y = t[hs][t8 + 1]; a.z = t[hs][t8 + 2]; a.w = t[hs][t8 + 3];
    b.x = t[hs][t8 + 4]; b.y = t[hs][t8 + 5]; b.z = t[hs][t8 + 6]; b.w = t[hs][t8 + 7];
    u16* dst = vt + (size_t)(g * 64 + hs) * T_SEQ + tb * 64 + t8;
    *reinterpret_cast<ushort4*>(dst) = a;
    *reinterpret_cast<ushort4*>(dst + 4) = b;
  }
}

// ---------------------------------------------------------------------------
// Fused MFMA attention.  Block = (head h, q-tile of 128 rows), 4 waves.
// Swapped QK^T: S^T = mfma(K, Q)  (col = q is lane-local).
// Phase 1: online row max m / sumexp l.  Phase 2: bitwise-identical score
// recompute -> w levels -> per-wave LDS W[q][k] -> O^T = mfma(V^T, W^T).
// Epilogue: O^T -> LDS f32 -> coalesced split hi/lo y writes.
// All tiles XOR-swizzled: byte ^= ((row&7)<<4), row stride 128B.
// ---------------------------------------------------------------------------
__global__ __launch_bounds__(256) void attn_fused(const u16* __restrict__ qkv,
                                                  const u16* __restrict__ vt,
                                                  u16* __restrict__ y_hi,
                                                  u16* __restrict__ y_lo,
                                                  const float* __restrict__ aq_p,
                                                  const float* __restrict__ asm_p) {
  // balanced (head, qtile) map: co-resident blocks c, c+256 get qb and 15-qb
  const int c = blockIdx.x;
  const int chi = c >> 8, mid = (c >> 4) & 15, clo = c & 15;
  const int h = mid + (chi << 4);
  const int qb = chi ? (15 - clo) : clo;
  const int g = h >> 2, s = h & 3;
  const int q_col = (g * 6 + s) * 64;
  const int k_col = (g * 6 + 4) * 64;

  __shared__ __align__(16) char lds_raw[49152];
  u16* Ks  = (u16*)(lds_raw + 16384);   // [64][64] swizzled
  u16* Vts = (u16*)(lds_raw + 24576);   // [64][64] (hs x k) swizzled

  const int tid = threadIdx.x;
  const int w = tid >> 6, lane = tid & 63;
  const int fr = lane & 15, gg = lane >> 4;
  char* myW = lds_raw + 32768 + w * 4096;  // per-wave [32][64] swizzled

  const float sq = (*aq_p) * (1.0f / 63.0f);
  const float scale = sq * sq * 0.125f;
  const float alpha_sm = *asm_p;
  const float scale_y = (alpha_sm * (1.0f / 63.0f)) * sq;
  const int nkt = 2 * qb + 2;

  // ---- stage Q [128][64] swizzled (each wave stages its own 32 rows)
#pragma unroll
  for (int i = 0; i < 4; ++i) {
    const int cb = (w * 4 + i) * 64;
    const int ch = cb + lane;
    const int row = ch >> 3;
    const int sb = ((ch & 7) * 16) ^ ((row & 7) << 4);
    llds16(qkv + (size_t)(qb * 128 + row) * QKV_DIM + q_col + (sb >> 1),
           lds_raw + cb * 16);
  }
  __syncthreads();
  bf16x8 qf[2][2];  // B-frags: q = w*32 + nq*16 + fr, k(hs) = ks*32 + gg*8
#pragma unroll
  for (int nq = 0; nq < 2; ++nq)
#pragma unroll
    for (int ks = 0; ks < 2; ++ks) {
      const int qr = w * 32 + nq * 16 + fr;
      qf[nq][ks] = *reinterpret_cast<const bf16x8*>(
          lds_raw + ((qr * 128 + ks * 64 + gg * 16) ^ ((qr & 7) << 4)));
    }

  float m_run[2] = {-INFINITY, -INFINITY};
  float l_run[2] = {0.0f, 0.0f};

  // ---- phase 1: stats
  for (int kt = 0; kt < nkt; ++kt) {
    __syncthreads();
#pragma unroll
    for (int i = 0; i < 2; ++i) {
      const int cb = (w * 2 + i) * 64;
      const int ch = cb + lane;
      const int row = ch >> 3;
      const int sb = ((ch & 7) * 16) ^ ((row & 7) << 4);
      llds16(qkv + (size_t)(kt * 64 + row) * QKV_DIM + k_col + (sb >> 1),
             (char*)Ks + cb * 16);
    }
    __syncthreads();
    f32x4 sac[4][2];
    const f32x4 zero = {0.f, 0.f, 0.f, 0.f};
#pragma unroll
    for (int mk = 0; mk < 4; ++mk)
#pragma unroll
      for (int nq = 0; nq < 2; ++nq) sac[mk][nq] = zero;
#pragma unroll
    for (int ks = 0; ks < 2; ++ks)
#pragma unroll
      for (int mk = 0; mk < 4; ++mk) {
        const int kr = mk * 16 + fr;
        bf16x8 kf = *reinterpret_cast<const bf16x8*>(
            (char*)Ks + ((kr * 128 + ks * 64 + gg * 16) ^ ((kr & 7) << 4)));
#pragma unroll
        for (int nq = 0; nq < 2; ++nq)
          sac[mk][nq] = __builtin_amdgcn_mfma_f32_16x16x32_bf16(kf, qf[nq][ks], sac[mk][nq], 0, 0, 0);
      }
    const bool edge = (kt >= 2 * qb);
#pragma unroll
    for (int nq = 0; nq < 2; ++nq) {
      const int qglob = qb * 128 + w * 32 + nq * 16 + fr;
      float vm = -INFINITY;
#pragma unroll
      for (int mk = 0; mk < 4; ++mk)
#pragma unroll
        for (int jj = 0; jj < 4; ++jj) {
          float sv = sac[mk][nq][jj] * scale;
          if (edge && (kt * 64 + mk * 16 + gg * 4 + jj > qglob)) sv = -INFINITY;
          vm = fmaxf(vm, sv);
        }
      vm = fmaxf(vm, __shfl_xor(vm, 16));
      vm = fmaxf(vm, __shfl_xor(vm, 32));
      const float mn = fmaxf(m_run[nq], vm);
      float p = 0.0f;
#pragma unroll
      for (int mk = 0; mk < 4; ++mk)
#pragma unroll
        for (int jj = 0; jj < 4; ++jj) {
          float sv = sac[mk][nq][jj] * scale;
          if (edge && (kt * 64 + mk * 16 + gg * 4 + jj > qglob)) sv = -INFINITY;
          p += expf(sv - mn);
        }
      p += __shfl_xor(p, 16);
      p += __shfl_xor(p, 32);
      l_run[nq] = l_run[nq] * expf(m_run[nq] - mn) + p;
      m_run[nq] = mn;
    }
  }

  const float linv[2] = {1.0f / l_run[0], 1.0f / l_run[1]};
  f32x4 oac[4][2];
  {
    const f32x4 zero = {0.f, 0.f, 0.f, 0.f};
#pragma unroll
    for (int mh = 0; mh < 4; ++mh)
#pragma unroll
      for (int nq = 0; nq < 2; ++nq) oac[mh][nq] = zero;
  }

  // ---- phase 2: recompute + quantize + PV
  for (int kt = 0; kt < nkt; ++kt) {
    __syncthreads();
#pragma unroll
    for (int i = 0; i < 2; ++i) {
      const int cb = (w * 2 + i) * 64;
      const int ch = cb + lane;
      const int row = ch >> 3;
      const int sb = ((ch & 7) * 16) ^ ((row & 7) << 4);
      llds16(qkv + (size_t)(kt * 64 + row) * QKV_DIM + k_col + (sb >> 1),
             (char*)Ks + cb * 16);
      llds16(vt + (size_t)(g * 64 + row) * T_SEQ + kt * 64 + (sb >> 1),
             (char*)Vts + cb * 16);
    }
    __syncthreads();
    f32x4 sac[4][2];
    const f32x4 zero = {0.f, 0.f, 0.f, 0.f};
#pragma unroll
    for (int mk = 0; mk < 4; ++mk)
#pragma unroll
      for (int nq = 0; nq < 2; ++nq) sac[mk][nq] = zero;
#pragma unroll
    for (int ks = 0; ks < 2; ++ks)
#pragma unroll
      for (int mk = 0; mk < 4; ++mk) {
        const int kr = mk * 16 + fr;
        bf16x8 kf = *reinterpret_cast<const bf16x8*>(
            (char*)Ks + ((kr * 128 + ks * 64 + gg * 16) ^ ((kr & 7) << 4)));
#pragma unroll
        for (int nq = 0; nq < 2; ++nq)
          sac[mk][nq] = __builtin_amdgcn_mfma_f32_16x16x32_bf16(kf, qf[nq][ks], sac[mk][nq], 0, 0, 0);
      }
    const bool edge = (kt >= 2 * qb);
    // w levels -> per-wave W[q][k] (packed b32 pair writes, swizzled)
#pragma unroll
    for (int nq = 0; nq < 2; ++nq) {
      const int qglob = qb * 128 + w * 32 + nq * 16 + fr;
      const int qloc = nq * 16 + fr;
      const float mr = m_run[nq], li = linv[nq];
#pragma unroll
      for (int mk = 0; mk < 4; ++mk) {
        u32 pk[2];
#pragma unroll
        for (int dd = 0; dd < 2; ++dd) {
          u32 lo16, hi16;
          {
            float sv = sac[mk][nq][dd * 2] * scale;
            if (edge && (kt * 64 + mk * 16 + gg * 4 + dd * 2 > qglob)) sv = -INFINITY;
            float wv = expf(sv - mr) * li;
            lo16 = f2bf(rintf(fminf(wv / alpha_sm, 1.0f) * 63.0f));
          }
          {
            float sv = sac[mk][nq][dd * 2 + 1] * scale;
            if (edge && (kt * 64 + mk * 16 + gg * 4 + dd * 2 + 1 > qglob)) sv = -INFINITY;
            float wv = expf(sv - mr) * li;
            hi16 = f2bf(rintf(fminf(wv / alpha_sm, 1.0f) * 63.0f));
          }
          pk[dd] = (hi16 << 16) | lo16;
        }
        const int b0 = (qloc * 128 + (mk * 16 + gg * 4) * 2) ^ ((qloc & 7) << 4);
        *reinterpret_cast<u32*>(myW + b0) = pk[0];
        *reinterpret_cast<u32*>(myW + b0 + 4) = pk[1];
      }
    }
    // PV: O^T += V^T @ W^T   (same-wave W round-trip; lgkmcnt ordering)
#pragma unroll
    for (int ks = 0; ks < 2; ++ks) {
      bf16x8 wf[2];
#pragma unroll
      for (int nq = 0; nq < 2; ++nq) {
        const int qloc = nq * 16 + fr;
        wf[nq] = *reinterpret_cast<const bf16x8*>(
            myW + ((qloc * 128 + ks * 64 + gg * 16) ^ ((qloc & 7) << 4)));
      }
#pragma unroll
      for (int mh = 0; mh < 4; ++mh) {
        const int hr = mh * 16 + fr;
        bf16x8 vf = *reinterpret_cast<const bf16x8*>(
            (char*)Vts + ((hr * 128 + ks * 64 + gg * 16) ^ ((hr & 7) << 4)));
#pragma unroll
        for (int nq = 0; nq < 2; ++nq)
          oac[mh][nq] = __builtin_amdgcn_mfma_f32_16x16x32_bf16(vf, wf[nq], oac[mh][nq], 0, 0, 0);
      }
    }
  }

  // ---- epilogue: O^T -> per-wave f32 LDS [32 q][64 hs] -> coalesced y writes
  __syncthreads();
  float* osc = (float*)(lds_raw + w * 8192);
#pragma unroll
  for (int mh = 0; mh < 4; ++mh)
#pragma unroll
    for (int nq = 0; nq < 2; ++nq) {
      const int qloc = nq * 16 + fr;
#pragma unroll
      for (int jj = 0; jj < 4; ++jj) {
        const int hs = mh * 16 + gg * 4 + jj;
        *reinterpret_cast<float*>(
            (char*)osc + ((qloc * 256 + hs * 4) ^ ((qloc & 7) << 4))) =
            oac[mh][nq][jj] * scale_y;
      }
    }
  __syncthreads();
  const int qp = lane >> 1, hf = lane & 1;
  const int qrow = qb * 128 + w * 32 + qp;
  u16* dh = y_hi + (size_t)qrow * C_DIM + h * 64 + hf * 32;
  u16* dl = y_lo + (size_t)qrow * C_DIM + h * 64 + hf * 32;
#pragma unroll
  for (int u = 0; u < 8; ++u) {
    f32x4 v = *reinterpret_cast<const f32x4*>(
        (char*)osc + ((qp * 256 + hf * 128 + u * 16) ^ ((qp & 7) << 4)));
    ushort4 hh, ll;
    u16 t0 = f2bf(v[0]); hh.x = t0; ll.x = f2bf(v[0] - bf2f(t0));
    u16 t1 = f2bf(v[1]); hh.y = t1; ll.y = f2bf(v[1] - bf2f(t1));
    u16 t2 = f2bf(v[2]); hh.z = t2; ll.z = f2bf(v[2] - bf2f(t2));
    u16 t3 = f2bf(v[3]); hh.w = t3; ll.w = f2bf(v[3] - bf2f(t3));
    *reinterpret_cast<ushort4*>(dh + u * 4) = hh;
    *reinterpret_cast<ushort4*>(dl + u * 4) = ll;
  }
}

// ---------------------------------------------------------------------------
extern "C" void kernel_launch(void* const* d_in, const int* in_sizes, int n_in,
                              void* d_out, int out_size, void* d_ws, size_t ws_size,
                              hipStream_t stream) {
  (void)in_sizes; (void)n_in; (void)out_size; (void)ws_size;
  const float* x      = (const float*)d_in[0];
  const float* w1     = (const float*)d_in[1];
  const float* w2     = (const float*)d_in[2];
  const float* a1     = (const float*)d_in[3];
  const float* a2     = (const float*)d_in[4];
  const float* aq     = (const float*)d_in[5];
  const float* a_sm   = (const float*)d_in[6];
  const float* attn_w = (const float*)d_in[7];
  const float* proj_w = (const float*)d_in[8];
  const float* fc1_w  = (const float*)d_in[9];
  const float* fc2_w  = (const float*)d_in[10];
  const float* mlp_w  = (const float*)d_in[11];
  float* out = (float*)d_out;

  // Workspace (bytes):
  //   [0, 25165824)         W: weight split (hi | lo)
  //   [25165824, 33554432)  nb: n1/n2 integer levels (bf16)
  //   [33554432, ...)       A: qkv_i(12.6M) | y_hi(8.4M) | y_lo(8.4M) | vt(2M)
  //                         later reused as ghi | glo
  char* ws = (char*)d_ws;
  u16* Whi   = (u16*)ws;
  u16* nb    = (u16*)(ws + 25165824);
  char* A    = ws + 33554432;
  u16* qkv_i = (u16*)A;
  u16* y_hi  = (u16*)(A + 12582912);
  u16* y_lo  = (u16*)(A + 20971520);
  u16* vt    = (u16*)(A + 29360128);
  u16* ghi   = (u16*)A;
  u16* glo   = (u16*)(A + 11534336);

  // 1) n1 levels
  rmsnorm_quant_int<<<T_SEQ, 256, 0, stream>>>(x, w1, a1, nb);
  // 2) qkv = quant levels of (n1 @ attn_w^T)
  conv_split<<<dim3(QKV_DIM, 2), 256, 0, stream>>>(attn_w, C_DIM, C_DIM,
                                                   Whi, Whi + (size_t)QKV_DIM * C_DIM);
  gemm_mfma<2, 1><<<dim3(QKV_DIM / 128, T_SEQ / 128), 256, 0, stream>>>(
      nb, nullptr, Whi, Whi + (size_t)QKV_DIM * C_DIM, nullptr, qkv_i, nullptr,
      nullptr, nullptr, a1, aq, T_SEQ, QKV_DIM, C_DIM);
  // 3) attention (MFMA)
  v_transpose<<<dim3(32, 8), 256, 0, stream>>>(qkv_i, vt);
  attn_fused<<<512, 256, 0, stream>>>(qkv_i, vt, y_hi, y_lo, aq, a_sm);
  // 4) x2 = x + y @ proj_w^T
  conv_split<<<dim3(C_DIM, 2), 256, 0, stream>>>(proj_w, C_DIM, C_DIM,
                                                 Whi, Whi + (size_t)C_DIM * C_DIM);
  gemm_mfma<3, 0><<<dim3(C_DIM / 128, T_SEQ / 128), 256, 0, stream>>>(
      y_hi, y_lo, Whi, Whi + (size_t)C_DIM * C_DIM, out, nullptr, x,
      nullptr, nullptr, nullptr, nullptr, T_SEQ, C_DIM, C_DIM);
  // 5) n2 levels
  rmsnorm_quant_int<<<T_SEQ, 256, 0, stream>>>(out, w2, a2, nb);
  // 6-8) MLP in two FF halves
  for (int h = 0; h < 2; ++h) {
    const float* fc1h = fc1_w + (size_t)h * FF_HALF * C_DIM;
    const float* fc2h = fc2_w + (size_t)h * FF_HALF * C_DIM;
    const float* mlph = mlp_w + (size_t)h * FF_HALF;
    conv_split<<<dim3(FF_HALF, 2), 256, 0, stream>>>(fc1h, C_DIM, C_DIM,
                                                     Whi, Whi + (size_t)FF_HALF * C_DIM);
    gemm_mfma<2, 2><<<dim3(FF_HALF / 128, T_SEQ / 128), 256, 0, stream>>>(
        nb, nullptr, Whi, Whi + (size_t)FF_HALF * C_DIM, nullptr, nullptr, nullptr,
        ghi, glo, a2, nullptr, T_SEQ, FF_HALF, C_DIM);
    conv_split<<<dim3(FF_HALF, 2), 256, 0, stream>>>(fc2h, C_DIM, C_DIM,
                                                     Whi, Whi + (size_t)FF_HALF * C_DIM);
    gemm_mfma<2, 3><<<dim3(FF_HALF / 128, T_SEQ / 128), 256, 0, stream>>>(
        nb, nullptr, Whi, Whi + (size_t)FF_HALF * C_DIM, nullptr, nullptr, nullptr,
        ghi, glo, a2, nullptr, T_SEQ, FF_HALF, C_DIM);
    conv_split<<<dim3(C_DIM, 3), 256, 0, stream>>>(mlph, FF_DIM, FF_HALF,
                                                   Whi, Whi + (size_t)C_DIM * FF_HALF);
    gemm_mfma<3, 0><<<dim3(C_DIM / 128, T_SEQ / 128), 256, 0, stream>>>(
        ghi, glo, Whi, Whi + (size_t)C_DIM * FF_HALF, out, nullptr, out,
        nullptr, nullptr, nullptr, nullptr, T_SEQ, C_DIM, FF_HALF);
  }
}

// Round 5
// 1008.149 us; speedup vs baseline: 3.5302x; 1.1745x over previous
//
#include <hip/hip_runtime.h>
#include <hip/hip_bf16.h>
#include <math.h>

// ---------------------------------------------------------------------------
// Round 5: (a) GEMM 2-phase double-buffered prefetch (T3-minimum) — at 1
// block/CU the stage->barrier->compute chain was fully serialized; (b) attn
// softmax in log2 domain on hardware v_exp_f32 + v_cvt_pk_bf16_f32 packing.
// Attention structure, GEMM math, layouts, workspace: unchanged from round 4
// (verified, absmax 0.015625).
//   B=1, T=2048, C=2048, H=32, G=8, HS=64, FF=5632, LEVELS=63
// ---------------------------------------------------------------------------

#define T_SEQ 2048
#define C_DIM 2048
#define QKV_DIM 3072
#define FF_DIM 5632
#define FF_HALF 2816
#define LOG2E 1.44269504088896340736f

typedef short bf16x8 __attribute__((ext_vector_type(8)));
typedef float f32x4 __attribute__((ext_vector_type(4)));
typedef unsigned short u16;
typedef unsigned int u32;

__device__ __forceinline__ u16 f2bf(float f) {
  __hip_bfloat16 h = __float2bfloat16(f);   // RNE
  return *reinterpret_cast<u16*>(&h);
}
__device__ __forceinline__ float bf2f(u16 u) {
  __hip_bfloat16 h;
  *reinterpret_cast<u16*>(&h) = u;
  return __bfloat162float(h);
}

__device__ __forceinline__ float qint(float v, float alpha) {
  float xd = fmaxf(v, 0.0f) / alpha;
  xd = fminf(xd, 1.0f);
  return rintf(xd * 63.0f);
}

// hardware 2^x (TRANS pipe, 1 instr).  exp2(-inf)=0.
__device__ __forceinline__ float exp2_hw(float x) {
  float r;
  asm("v_exp_f32 %0, %1" : "=v"(r) : "v"(x));
  return r;
}
// pack two f32 -> two bf16 (RNE) in one instr; lo -> bits[15:0], hi -> [31:16]
__device__ __forceinline__ u32 cvtpk_bf16(float lo, float hi) {
  u32 r;
  asm("v_cvt_pk_bf16_f32 %0, %1, %2" : "=v"(r) : "v"(lo), "v"(hi));
  return r;
}

__device__ __forceinline__ void llds16(const void* g, void* l) {
  __builtin_amdgcn_global_load_lds(
      (const __attribute__((address_space(1))) unsigned int*)g,
      (__attribute__((address_space(3))) unsigned int*)l, 16, 0, 0);
}

// ---------------------------------------------------------------------------
// RMSNorm + quant -> integer levels stored as bf16 (exact).
// ---------------------------------------------------------------------------
__global__ __launch_bounds__(256) void rmsnorm_quant_int(const float* __restrict__ x,
                                                         const float* __restrict__ w,
                                                         const float* __restrict__ alpha_p,
                                                         u16* __restrict__ out) {
  const int row = blockIdx.x;
  const float* xr = x + (size_t)row * C_DIM;
  const int base = threadIdx.x * 8;
  float4 v0 = *reinterpret_cast<const float4*>(xr + base);
  float4 v1 = *reinterpret_cast<const float4*>(xr + base + 4);
  float xv[8] = {v0.x, v0.y, v0.z, v0.w, v1.x, v1.y, v1.z, v1.w};
  float ss = 0.0f;
#pragma unroll
  for (int k = 0; k < 8; ++k) ss = fmaf(xv[k], xv[k], ss);
#pragma unroll
  for (int m = 1; m < 64; m <<= 1) ss += __shfl_xor(ss, m);
  __shared__ float wsum[4];
  const int lane = threadIdx.x & 63, wv = threadIdx.x >> 6;
  if (lane == 0) wsum[wv] = ss;
  __syncthreads();
  const float tot = wsum[0] + wsum[1] + wsum[2] + wsum[3];
  const float rs = 1.0f / sqrtf(tot * (1.0f / 2048.0f) + 1e-5f);
  const float alpha = *alpha_p;
  u16 ov[8];
#pragma unroll
  for (int k = 0; k < 8; ++k) ov[k] = f2bf(qint((w[base + k] * xv[k]) * rs, alpha));
  u16* orow = out + (size_t)row * C_DIM + base;
#pragma unroll
  for (int k = 0; k < 2; ++k) {
    ushort4 u;
    u.x = ov[k * 4]; u.y = ov[k * 4 + 1]; u.z = ov[k * 4 + 2]; u.w = ov[k * 4 + 3];
    *reinterpret_cast<ushort4*>(orow + k * 4) = u;
  }
}

// ---------------------------------------------------------------------------
// fp32 -> (hi, lo) bf16 planes.
// ---------------------------------------------------------------------------
__global__ __launch_bounds__(256) void conv_split(const float* __restrict__ src, int ld,
                                                  int cols,
                                                  u16* __restrict__ hi, u16* __restrict__ lo) {
  const int r = blockIdx.x;
  const int c4 = (blockIdx.y * 256 + threadIdx.x) * 4;
  if (c4 >= cols) return;
  float4 v = *reinterpret_cast<const float4*>(&src[(size_t)r * ld + c4]);
  float f[4] = {v.x, v.y, v.z, v.w};
  ushort4 h, l;
  u16 hh[4], ll[4];
#pragma unroll
  for (int j = 0; j < 4; ++j) {
    hh[j] = f2bf(f[j]);
    ll[j] = f2bf(f[j] - bf2f(hh[j]));
  }
  h.x = hh[0]; h.y = hh[1]; h.z = hh[2]; h.w = hh[3];
  l.x = ll[0]; l.y = ll[1]; l.z = ll[2]; l.w = ll[3];
  const size_t o = (size_t)r * cols + c4;
  *reinterpret_cast<ushort4*>(&hi[o]) = h;
  *reinterpret_cast<ushort4*>(&lo[o]) = l;
}

// ---------------------------------------------------------------------------
// Multi-term bf16 MFMA GEMM with double-buffered LDS prefetch.
// MODE 2: terms (A0,B0)+(A0,B1).  MODE 3: (A0,B0)+(A1,B0)+(A0,B1).
// EPI 0: Cf = aux + acc;  EPI 1: quant levels;  EPI 2: split planes;
// EPI 3: gu = silu(g)*acc -> split planes (in place).
// ---------------------------------------------------------------------------
template <int MODE, int EPI>
__global__ __launch_bounds__(256) void gemm_mfma(
    const u16* __restrict__ A0, const u16* __restrict__ A1,
    const u16* __restrict__ B0, const u16* __restrict__ B1,
    float* __restrict__ Cf, u16* __restrict__ Cq, const float* __restrict__ auxf,
    u16* __restrict__ p_hi, u16* __restrict__ p_lo,
    const float* __restrict__ sA_p, const float* __restrict__ aQ_p,
    int M, int N, int K) {
  constexpr int NT = (MODE == 2) ? 3 : 4;
  __shared__ __align__(16) u16 lds[2 * NT * 4096];   // double-buffered

  const int tid = threadIdx.x;
  const int nwg = gridDim.x * gridDim.y;
  const int wg = blockIdx.y * gridDim.x + blockIdx.x;
  const int swz = (wg & 7) * (nwg >> 3) + (wg >> 3);
  const int bx = swz % gridDim.x, by = swz / gridDim.x;
  const int row0 = by * 128, col0 = bx * 128;

  const int w = tid >> 6, lane = tid & 63;
  const int wr = w >> 1, wc = w & 1;
  const int fr = lane & 15, ko = (lane >> 4) * 8;

  const int c0 = w * 128 + lane;
  const int r_a = c0 >> 2;
  const int s_a = (c0 & 3) * 8;

  u16* cu = lds;
  u16* nx = lds + NT * 4096;

  auto stage = [&](u16* base, int kt) {
    {
      const u16* g0 = A0 + (size_t)(row0 + r_a) * K + kt + s_a;
      const u16* g1 = A0 + (size_t)(row0 + r_a + 16) * K + kt + s_a;
      llds16(g0, base + (w * 128) * 8);
      llds16(g1, base + (w * 128 + 64) * 8);
    }
    if constexpr (MODE == 3) {
      const u16* g0 = A1 + (size_t)(row0 + r_a) * K + kt + s_a;
      const u16* g1 = A1 + (size_t)(row0 + r_a + 16) * K + kt + s_a;
      llds16(g0, base + 4096 + (w * 128) * 8);
      llds16(g1, base + 4096 + (w * 128 + 64) * 8);
    }
    {
      u16* dst = base + ((MODE == 2) ? 4096 : 8192);
      const u16* g0 = B0 + (size_t)(col0 + r_a) * K + kt + s_a;
      const u16* g1 = B0 + (size_t)(col0 + r_a + 16) * K + kt + s_a;
      llds16(g0, dst + (w * 128) * 8);
      llds16(g1, dst + (w * 128 + 64) * 8);
    }
    {
      u16* dst = base + ((MODE == 2) ? 8192 : 12288);
      const u16* g0 = B1 + (size_t)(col0 + r_a) * K + kt + s_a;
      const u16* g1 = B1 + (size_t)(col0 + r_a + 16) * K + kt + s_a;
      llds16(g0, dst + (w * 128) * 8);
      llds16(g1, dst + (w * 128 + 64) * 8);
    }
  };

  f32x4 acc[4][4];
  const f32x4 zero = {0.f, 0.f, 0.f, 0.f};
#pragma unroll
  for (int m = 0; m < 4; ++m)
#pragma unroll
    for (int n = 0; n < 4; ++n) acc[m][n] = zero;

  stage(cu, 0);
  __syncthreads();

  for (int kt = 0;; kt += 32) {
    const bool more = (kt + 32 < K);
    if (more) stage(nx, kt + 32);   // prefetch overlaps this tile's compute

    const u16* tA0 = cu;
    const u16* Bhi = cu + ((MODE == 2) ? 4096 : 8192);
    const u16* Blo = cu + ((MODE == 2) ? 8192 : 12288);
    bf16x8 a0f[4], bhf[4], blf[4];
#pragma unroll
    for (int m = 0; m < 4; ++m)
      a0f[m] = *reinterpret_cast<const bf16x8*>(&tA0[(wr * 64 + m * 16 + fr) * 32 + ko]);
#pragma unroll
    for (int n = 0; n < 4; ++n) {
      bhf[n] = *reinterpret_cast<const bf16x8*>(&Bhi[(wc * 64 + n * 16 + fr) * 32 + ko]);
      blf[n] = *reinterpret_cast<const bf16x8*>(&Blo[(wc * 64 + n * 16 + fr) * 32 + ko]);
    }
    if constexpr (MODE == 2) {
#pragma unroll
      for (int m = 0; m < 4; ++m)
#pragma unroll
        for (int n = 0; n < 4; ++n) {
          acc[m][n] = __builtin_amdgcn_mfma_f32_16x16x32_bf16(a0f[m], bhf[n], acc[m][n], 0, 0, 0);
          acc[m][n] = __builtin_amdgcn_mfma_f32_16x16x32_bf16(a0f[m], blf[n], acc[m][n], 0, 0, 0);
        }
    } else {
      bf16x8 a1f[4];
#pragma unroll
      for (int m = 0; m < 4; ++m)
        a1f[m] = *reinterpret_cast<const bf16x8*>(&cu[4096 + (wr * 64 + m * 16 + fr) * 32 + ko]);
#pragma unroll
      for (int m = 0; m < 4; ++m)
#pragma unroll
        for (int n = 0; n < 4; ++n) {
          acc[m][n] = __builtin_amdgcn_mfma_f32_16x16x32_bf16(a0f[m], bhf[n], acc[m][n], 0, 0, 0);
          acc[m][n] = __builtin_amdgcn_mfma_f32_16x16x32_bf16(a1f[m], bhf[n], acc[m][n], 0, 0, 0);
          acc[m][n] = __builtin_amdgcn_mfma_f32_16x16x32_bf16(a0f[m], blf[n], acc[m][n], 0, 0, 0);
        }
    }
    if (!more) break;
    __syncthreads();   // drains prefetch vmcnt + this tile's readers
    u16* t = cu; cu = nx; nx = t;
  }

  float sA = 1.0f, aQ = 1.0f;
  if constexpr (EPI == 1) { sA = (*sA_p) * (1.0f / 63.0f); aQ = *aQ_p; }
  if constexpr (EPI == 2 || EPI == 3) { sA = (*sA_p) * (1.0f / 63.0f); }
#pragma unroll
  for (int m = 0; m < 4; ++m)
#pragma unroll
    for (int n = 0; n < 4; ++n) {
      const int gcol = col0 + wc * 64 + n * 16 + fr;
#pragma unroll
      for (int j = 0; j < 4; ++j) {
        const int grow = row0 + wr * 64 + m * 16 + (lane >> 4) * 4 + j;
        const size_t idx = (size_t)grow * N + gcol;
        const float v = acc[m][n][j];
        if constexpr (EPI == 0) {
          Cf[idx] = auxf[idx] + v;
        } else if constexpr (EPI == 1) {
          float t = v * sA;
          float xd = fminf(fmaxf(t, 0.0f) / aQ, 1.0f);
          Cq[idx] = f2bf(rintf(xd * 63.0f));
        } else if constexpr (EPI == 2) {
          float t = v * sA;
          u16 h = f2bf(t);
          p_hi[idx] = h;
          p_lo[idx] = f2bf(t - bf2f(h));
        } else if constexpr (EPI == 3) {
          float gg = bf2f(p_hi[idx]) + bf2f(p_lo[idx]);
          float u = v * sA;
          float gu = (gg / (1.0f + expf(-gg))) * u;
          u16 h = f2bf(gu);
          p_hi[idx] = h;
          p_lo[idx] = f2bf(gu - bf2f(h));
        }
      }
    }
}

// ---------------------------------------------------------------------------
// V pre-transpose: vt[g][hs][t] = qkv[t][(g*6+5)*64 + hs]  (bf16 levels)
// ---------------------------------------------------------------------------
__global__ __launch_bounds__(256) void v_transpose(const u16* __restrict__ qkv,
                                                   u16* __restrict__ vt) {
  const int tb = blockIdx.x, g = blockIdx.y;
  const int vcol = (g * 6 + 5) * 64;
  __shared__ u16 t[64][72];
  const int tid = threadIdx.x;
#pragma unroll
  for (int i = 0; i < 2; ++i) {
    const int ch = i * 256 + tid;
    const int row = ch >> 3, c8 = (ch & 7) * 8;
    bf16x8 v = *reinterpret_cast<const bf16x8*>(
        qkv + (size_t)(tb * 64 + row) * QKV_DIM + vcol + c8);
#pragma unroll
    for (int j = 0; j < 8; ++j) t[c8 + j][row] = (u16)v[j];
  }
  __syncthreads();
#pragma unroll
  for (int i = 0; i < 2; ++i) {
    const int ch = i * 256 + tid;
    const int hs = ch >> 3, t8 = (ch & 7) * 8;
    ushort4 a, b;
    a.x = t[hs][t8];     a.y = t[hs][t8 + 1]; a.z = t[hs][t8 + 2]; a.w = t[hs][t8 + 3];
    b.x = t[hs][t8 + 4]; b.y = t[hs][t8 + 5]; b.z = t[hs][t8 + 6]; b.w = t[hs][t8 + 7];
    u16* dst = vt + (size_t)(g * 64 + hs) * T_SEQ + tb * 64 + t8;
    *reinterpret_cast<ushort4*>(dst) = a;
    *reinterpret_cast<ushort4*>(dst + 4) = b;
  }
}

// ---------------------------------------------------------------------------
// Fused MFMA attention (structure as round 4; softmax in log2 domain).
// ---------------------------------------------------------------------------
__global__ __launch_bounds__(256) void attn_fused(const u16* __restrict__ qkv,
                                                  const u16* __restrict__ vt,
                                                  u16* __restrict__ y_hi,
                                                  u16* __restrict__ y_lo,
                                                  const float* __restrict__ aq_p,
                                                  const float* __restrict__ asm_p) {
  const int c = blockIdx.x;
  const int chi = c >> 8, mid = (c >> 4) & 15, clo = c & 15;
  const int h = mid + (chi << 4);
  const int qb = chi ? (15 - clo) : clo;
  const int g = h >> 2, s = h & 3;
  const int q_col = (g * 6 + s) * 64;
  const int k_col = (g * 6 + 4) * 64;

  __shared__ __align__(16) char lds_raw[49152];
  u16* Ks  = (u16*)(lds_raw + 16384);
  u16* Vts = (u16*)(lds_raw + 24576);

  const int tid = threadIdx.x;
  const int w = tid >> 6, lane = tid & 63;
  const int fr = lane & 15, gg = lane >> 4;
  char* myW = lds_raw + 32768 + w * 4096;

  const float sq = (*aq_p) * (1.0f / 63.0f);
  const float scale2 = sq * sq * 0.125f * LOG2E;   // score -> log2 domain
  const float alpha_sm = *asm_p;
  const float inv_a63 = 63.0f / alpha_sm;
  const float scale_y = (alpha_sm * (1.0f / 63.0f)) * sq;
  const int nkt = 2 * qb + 2;

  // ---- stage Q [128][64] swizzled
#pragma unroll
  for (int i = 0; i < 4; ++i) {
    const int cb = (w * 4 + i) * 64;
    const int ch = cb + lane;
    const int row = ch >> 3;
    const int sb = ((ch & 7) * 16) ^ ((row & 7) << 4);
    llds16(qkv + (size_t)(qb * 128 + row) * QKV_DIM + q_col + (sb >> 1),
           lds_raw + cb * 16);
  }
  __syncthreads();
  bf16x8 qf[2][2];
#pragma unroll
  for (int nq = 0; nq < 2; ++nq)
#pragma unroll
    for (int ks = 0; ks < 2; ++ks) {
      const int qr = w * 32 + nq * 16 + fr;
      qf[nq][ks] = *reinterpret_cast<const bf16x8*>(
          lds_raw + ((qr * 128 + ks * 64 + gg * 16) ^ ((qr & 7) << 4)));
    }

  float m_run[2] = {-INFINITY, -INFINITY};   // log2-domain running max
  float l_run[2] = {0.0f, 0.0f};

  // ---- phase 1: stats
  for (int kt = 0; kt < nkt; ++kt) {
    __syncthreads();
#pragma unroll
    for (int i = 0; i < 2; ++i) {
      const int cb = (w * 2 + i) * 64;
      const int ch = cb + lane;
      const int row = ch >> 3;
      const int sb = ((ch & 7) * 16) ^ ((row & 7) << 4);
      llds16(qkv + (size_t)(kt * 64 + row) * QKV_DIM + k_col + (sb >> 1),
             (char*)Ks + cb * 16);
    }
    __syncthreads();
    f32x4 sac[4][2];
    const f32x4 zero = {0.f, 0.f, 0.f, 0.f};
#pragma unroll
    for (int mk = 0; mk < 4; ++mk)
#pragma unroll
      for (int nq = 0; nq < 2; ++nq) sac[mk][nq] = zero;
#pragma unroll
    for (int ks = 0; ks < 2; ++ks)
#pragma unroll
      for (int mk = 0; mk < 4; ++mk) {
        const int kr = mk * 16 + fr;
        bf16x8 kf = *reinterpret_cast<const bf16x8*>(
            (char*)Ks + ((kr * 128 + ks * 64 + gg * 16) ^ ((kr & 7) << 4)));
#pragma unroll
        for (int nq = 0; nq < 2; ++nq)
          sac[mk][nq] = __builtin_amdgcn_mfma_f32_16x16x32_bf16(kf, qf[nq][ks], sac[mk][nq], 0, 0, 0);
      }
    const bool edge = (kt >= 2 * qb);
#pragma unroll
    for (int nq = 0; nq < 2; ++nq) {
      const int qglob = qb * 128 + w * 32 + nq * 16 + fr;
      float tv[16];
#pragma unroll
      for (int mk = 0; mk < 4; ++mk)
#pragma unroll
        for (int jj = 0; jj < 4; ++jj) {
          float t = sac[mk][nq][jj] * scale2;
          if (edge && (kt * 64 + mk * 16 + gg * 4 + jj > qglob)) t = -INFINITY;
          tv[mk * 4 + jj] = t;
        }
      float vm = tv[0];
#pragma unroll
      for (int i = 1; i < 16; ++i) vm = fmaxf(vm, tv[i]);
      vm = fmaxf(vm, __shfl_xor(vm, 16));
      vm = fmaxf(vm, __shfl_xor(vm, 32));
      const float mn = fmaxf(m_run[nq], vm);
      float p = 0.0f;
#pragma unroll
      for (int i = 0; i < 16; ++i) p += exp2_hw(tv[i] - mn);
      p += __shfl_xor(p, 16);
      p += __shfl_xor(p, 32);
      l_run[nq] = l_run[nq] * exp2_hw(m_run[nq] - mn) + p;
      m_run[nq] = mn;
    }
  }

  const float linv[2] = {1.0f / l_run[0], 1.0f / l_run[1]};
  f32x4 oac[4][2];
  {
    const f32x4 zero = {0.f, 0.f, 0.f, 0.f};
#pragma unroll
    for (int mh = 0; mh < 4; ++mh)
#pragma unroll
      for (int nq = 0; nq < 2; ++nq) oac[mh][nq] = zero;
  }

  // ---- phase 2: recompute + quantize + PV
  for (int kt = 0; kt < nkt; ++kt) {
    __syncthreads();
#pragma unroll
    for (int i = 0; i < 2; ++i) {
      const int cb = (w * 2 + i) * 64;
      const int ch = cb + lane;
      const int row = ch >> 3;
      const int sb = ((ch & 7) * 16) ^ ((row & 7) << 4);
      llds16(qkv + (size_t)(kt * 64 + row) * QKV_DIM + k_col + (sb >> 1),
             (char*)Ks + cb * 16);
      llds16(vt + (size_t)(g * 64 + row) * T_SEQ + kt * 64 + (sb >> 1),
             (char*)Vts + cb * 16);
    }
    __syncthreads();
    f32x4 sac[4][2];
    const f32x4 zero = {0.f, 0.f, 0.f, 0.f};
#pragma unroll
    for (int mk = 0; mk < 4; ++mk)
#pragma unroll
      for (int nq = 0; nq < 2; ++nq) sac[mk][nq] = zero;
#pragma unroll
    for (int ks = 0; ks < 2; ++ks)
#pragma unroll
      for (int mk = 0; mk < 4; ++mk) {
        const int kr = mk * 16 + fr;
        bf16x8 kf = *reinterpret_cast<const bf16x8*>(
            (char*)Ks + ((kr * 128 + ks * 64 + gg * 16) ^ ((kr & 7) << 4)));
#pragma unroll
        for (int nq = 0; nq < 2; ++nq)
          sac[mk][nq] = __builtin_amdgcn_mfma_f32_16x16x32_bf16(kf, qf[nq][ks], sac[mk][nq], 0, 0, 0);
      }
    const bool edge = (kt >= 2 * qb);
#pragma unroll
    for (int nq = 0; nq < 2; ++nq) {
      const int qglob = qb * 128 + w * 32 + nq * 16 + fr;
      const int qloc = nq * 16 + fr;
      const float mr = m_run[nq];
      const float cw = linv[nq] * inv_a63;
#pragma unroll
      for (int mk = 0; mk < 4; ++mk) {
        float lv[4];
#pragma unroll
        for (int jj = 0; jj < 4; ++jj) {
          float t = sac[mk][nq][jj] * scale2;
          if (edge && (kt * 64 + mk * 16 + gg * 4 + jj > qglob)) t = -INFINITY;
          lv[jj] = rintf(fminf(exp2_hw(t - mr) * cw, 63.0f));
        }
        const u32 pk0 = cvtpk_bf16(lv[0], lv[1]);
        const u32 pk1 = cvtpk_bf16(lv[2], lv[3]);
        const int b0 = (qloc * 128 + (mk * 16 + gg * 4) * 2) ^ ((qloc & 7) << 4);
        *reinterpret_cast<u32*>(myW + b0) = pk0;
        *reinterpret_cast<u32*>(myW + b0 + 4) = pk1;
      }
    }
    // PV: O^T += V^T @ W^T
#pragma unroll
    for (int ks = 0; ks < 2; ++ks) {
      bf16x8 wf[2];
#pragma unroll
      for (int nq = 0; nq < 2; ++nq) {
        const int qloc = nq * 16 + fr;
        wf[nq] = *reinterpret_cast<const bf16x8*>(
            myW + ((qloc * 128 + ks * 64 + gg * 16) ^ ((qloc & 7) << 4)));
      }
#pragma unroll
      for (int mh = 0; mh < 4; ++mh) {
        const int hr = mh * 16 + fr;
        bf16x8 vf = *reinterpret_cast<const bf16x8*>(
            (char*)Vts + ((hr * 128 + ks * 64 + gg * 16) ^ ((hr & 7) << 4)));
#pragma unroll
        for (int nq = 0; nq < 2; ++nq)
          oac[mh][nq] = __builtin_amdgcn_mfma_f32_16x16x32_bf16(vf, wf[nq], oac[mh][nq], 0, 0, 0);
      }
    }
  }

  // ---- epilogue
  __syncthreads();
  float* osc = (float*)(lds_raw + w * 8192);
#pragma unroll
  for (int mh = 0; mh < 4; ++mh)
#pragma unroll
    for (int nq = 0; nq < 2; ++nq) {
      const int qloc = nq * 16 + fr;
#pragma unroll
      for (int jj = 0; jj < 4; ++jj) {
        const int hs = mh * 16 + gg * 4 + jj;
        *reinterpret_cast<float*>(
            (char*)osc + ((qloc * 256 + hs * 4) ^ ((qloc & 7) << 4))) =
            oac[mh][nq][jj] * scale_y;
      }
    }
  __syncthreads();
  const int qp = lane >> 1, hf = lane & 1;
  const int qrow = qb * 128 + w * 32 + qp;
  u16* dh = y_hi + (size_t)qrow * C_DIM + h * 64 + hf * 32;
  u16* dl = y_lo + (size_t)qrow * C_DIM + h * 64 + hf * 32;
#pragma unroll
  for (int u = 0; u < 8; ++u) {
    f32x4 v = *reinterpret_cast<const f32x4*>(
        (char*)osc + ((qp * 256 + hf * 128 + u * 16) ^ ((qp & 7) << 4)));
    ushort4 hh, ll;
    u16 t0 = f2bf(v[0]); hh.x = t0; ll.x = f2bf(v[0] - bf2f(t0));
    u16 t1 = f2bf(v[1]); hh.y = t1; ll.y = f2bf(v[1] - bf2f(t1));
    u16 t2 = f2bf(v[2]); hh.z = t2; ll.z = f2bf(v[2] - bf2f(t2));
    u16 t3 = f2bf(v[3]); hh.w = t3; ll.w = f2bf(v[3] - bf2f(t3));
    *reinterpret_cast<ushort4*>(dh + u * 4) = hh;
    *reinterpret_cast<ushort4*>(dl + u * 4) = ll;
  }
}

// ---------------------------------------------------------------------------
extern "C" void kernel_launch(void* const* d_in, const int* in_sizes, int n_in,
                              void* d_out, int out_size, void* d_ws, size_t ws_size,
                              hipStream_t stream) {
  (void)in_sizes; (void)n_in; (void)out_size; (void)ws_size;
  const float* x      = (const float*)d_in[0];
  const float* w1     = (const float*)d_in[1];
  const float* w2     = (const float*)d_in[2];
  const float* a1     = (const float*)d_in[3];
  const float* a2     = (const float*)d_in[4];
  const float* aq     = (const float*)d_in[5];
  const float* a_sm   = (const float*)d_in[6];
  const float* attn_w = (const float*)d_in[7];
  const float* proj_w = (const float*)d_in[8];
  const float* fc1_w  = (const float*)d_in[9];
  const float* fc2_w  = (const float*)d_in[10];
  const float* mlp_w  = (const float*)d_in[11];
  float* out = (float*)d_out;

  char* ws = (char*)d_ws;
  u16* Whi   = (u16*)ws;
  u16* nb    = (u16*)(ws + 25165824);
  char* A    = ws + 33554432;
  u16* qkv_i = (u16*)A;
  u16* y_hi  = (u16*)(A + 12582912);
  u16* y_lo  = (u16*)(A + 20971520);
  u16* vt    = (u16*)(A + 29360128);
  u16* ghi   = (u16*)A;
  u16* glo   = (u16*)(A + 11534336);

  // 1) n1 levels
  rmsnorm_quant_int<<<T_SEQ, 256, 0, stream>>>(x, w1, a1, nb);
  // 2) qkv = quant levels of (n1 @ attn_w^T)
  conv_split<<<dim3(QKV_DIM, 2), 256, 0, stream>>>(attn_w, C_DIM, C_DIM,
                                                   Whi, Whi + (size_t)QKV_DIM * C_DIM);
  gemm_mfma<2, 1><<<dim3(QKV_DIM / 128, T_SEQ / 128), 256, 0, stream>>>(
      nb, nullptr, Whi, Whi + (size_t)QKV_DIM * C_DIM, nullptr, qkv_i, nullptr,
      nullptr, nullptr, a1, aq, T_SEQ, QKV_DIM, C_DIM);
  // 3) attention (MFMA)
  v_transpose<<<dim3(32, 8), 256, 0, stream>>>(qkv_i, vt);
  attn_fused<<<512, 256, 0, stream>>>(qkv_i, vt, y_hi, y_lo, aq, a_sm);
  // 4) x2 = x + y @ proj_w^T
  conv_split<<<dim3(C_DIM, 2), 256, 0, stream>>>(proj_w, C_DIM, C_DIM,
                                                 Whi, Whi + (size_t)C_DIM * C_DIM);
  gemm_mfma<3, 0><<<dim3(C_DIM / 128, T_SEQ / 128), 256, 0, stream>>>(
      y_hi, y_lo, Whi, Whi + (size_t)C_DIM * C_DIM, out, nullptr, x,
      nullptr, nullptr, nullptr, nullptr, T_SEQ, C_DIM, C_DIM);
  // 5) n2 levels
  rmsnorm_quant_int<<<T_SEQ, 256, 0, stream>>>(out, w2, a2, nb);
  // 6-8) MLP in two FF halves
  for (int h = 0; h < 2; ++h) {
    const float* fc1h = fc1_w + (size_t)h * FF_HALF * C_DIM;
    const float* fc2h = fc2_w + (size_t)h * FF_HALF * C_DIM;
    const float* mlph = mlp_w + (size_t)h * FF_HALF;
    conv_split<<<dim3(FF_HALF, 2), 256, 0, stream>>>(fc1h, C_DIM, C_DIM,
                                                     Whi, Whi + (size_t)FF_HALF * C_DIM);
    gemm_mfma<2, 2><<<dim3(FF_HALF / 128, T_SEQ / 128), 256, 0, stream>>>(
        nb, nullptr, Whi, Whi + (size_t)FF_HALF * C_DIM, nullptr, nullptr, nullptr,
        ghi, glo, a2, nullptr, T_SEQ, FF_HALF, C_DIM);
    conv_split<<<dim3(FF_HALF, 2), 256, 0, stream>>>(fc2h, C_DIM, C_DIM,
                                                     Whi, Whi + (size_t)FF_HALF * C_DIM);
    gemm_mfma<2, 3><<<dim3(FF_HALF / 128, T_SEQ / 128), 256, 0, stream>>>(
        nb, nullptr, Whi, Whi + (size_t)FF_HALF * C_DIM, nullptr, nullptr, nullptr,
        ghi, glo, a2, nullptr, T_SEQ, FF_HALF, C_DIM);
    conv_split<<<dim3(C_DIM, 3), 256, 0, stream>>>(mlph, FF_DIM, FF_HALF,
                                                   Whi, Whi + (size_t)C_DIM * FF_HALF);
    gemm_mfma<3, 0><<<dim3(C_DIM / 128, T_SEQ / 128), 256, 0, stream>>>(
        ghi, glo, Whi, Whi + (size_t)C_DIM * FF_HALF, out, nullptr, out,
        nullptr, nullptr, nullptr, nullptr, T_SEQ, C_DIM, FF_HALF);
  }
}

// Round 8
// 995.752 us; speedup vs baseline: 3.5741x; 1.0125x over previous
//
#include <hip/hip_runtime.h>
#include <hip/hip_bf16.h>
#include <math.h>

// ---------------------------------------------------------------------------
// Round 6 (resubmit #2; benches in rounds 6 and 7 never ran - GPU acquisition
// timeouts).  Weight hi/lo split fused INTO the GEMM (stage raw fp32 B tiles
// via global_load_lds, derive bf16 hi/lo planes in-register at frag build; B
// tile XOR-swizzled (row&7)<<4 with inverse permutation on the global source).
// conv_split pass deleted; MLP collapsed to full-FF GEMMs (9 launches total).
// Attention / rmsnorm / epilogues unchanged from round 5 (verified).
//   B=1, T=2048, C=2048, H=32, G=8, HS=64, FF=5632, LEVELS=63
// ---------------------------------------------------------------------------

#define T_SEQ 2048
#define C_DIM 2048
#define QKV_DIM 3072
#define FF_DIM 5632
#define LOG2E 1.44269504088896340736f

typedef short bf16x8 __attribute__((ext_vector_type(8)));
typedef float f32x4 __attribute__((ext_vector_type(4)));
typedef unsigned int u32x4 __attribute__((ext_vector_type(4)));
typedef unsigned short u16;
typedef unsigned int u32;

__device__ __forceinline__ u16 f2bf(float f) {
  __hip_bfloat16 h = __float2bfloat16(f);   // RNE
  return *reinterpret_cast<u16*>(&h);
}
__device__ __forceinline__ float bf2f(u16 u) {
  __hip_bfloat16 h;
  *reinterpret_cast<u16*>(&h) = u;
  return __bfloat162float(h);
}

__device__ __forceinline__ float qint(float v, float alpha) {
  float xd = fmaxf(v, 0.0f) / alpha;
  xd = fminf(xd, 1.0f);
  return rintf(xd * 63.0f);
}

// hardware 2^x (TRANS pipe, 1 instr).  exp2(-inf)=0.
__device__ __forceinline__ float exp2_hw(float x) {
  float r;
  asm("v_exp_f32 %0, %1" : "=v"(r) : "v"(x));
  return r;
}
// pack two f32 -> two bf16 (RNE); lo -> bits[15:0], hi -> [31:16]
__device__ __forceinline__ u32 cvtpk_bf16(float lo, float hi) {
  u32 r;
  asm("v_cvt_pk_bf16_f32 %0, %1, %2" : "=v"(r) : "v"(lo), "v"(hi));
  return r;
}

__device__ __forceinline__ void llds16(const void* g, void* l) {
  __builtin_amdgcn_global_load_lds(
      (const __attribute__((address_space(1))) unsigned int*)g,
      (__attribute__((address_space(3))) unsigned int*)l, 16, 0, 0);
}

// ---------------------------------------------------------------------------
// RMSNorm + quant -> integer levels stored as bf16 (exact).
// ---------------------------------------------------------------------------
__global__ __launch_bounds__(256) void rmsnorm_quant_int(const float* __restrict__ x,
                                                         const float* __restrict__ w,
                                                         const float* __restrict__ alpha_p,
                                                         u16* __restrict__ out) {
  const int row = blockIdx.x;
  const float* xr = x + (size_t)row * C_DIM;
  const int base = threadIdx.x * 8;
  float4 v0 = *reinterpret_cast<const float4*>(xr + base);
  float4 v1 = *reinterpret_cast<const float4*>(xr + base + 4);
  float xv[8] = {v0.x, v0.y, v0.z, v0.w, v1.x, v1.y, v1.z, v1.w};
  float ss = 0.0f;
#pragma unroll
  for (int k = 0; k < 8; ++k) ss = fmaf(xv[k], xv[k], ss);
#pragma unroll
  for (int m = 1; m < 64; m <<= 1) ss += __shfl_xor(ss, m);
  __shared__ float wsum[4];
  const int lane = threadIdx.x & 63, wv = threadIdx.x >> 6;
  if (lane == 0) wsum[wv] = ss;
  __syncthreads();
  const float tot = wsum[0] + wsum[1] + wsum[2] + wsum[3];
  const float rs = 1.0f / sqrtf(tot * (1.0f / 2048.0f) + 1e-5f);
  const float alpha = *alpha_p;
  u16 ov[8];
#pragma unroll
  for (int k = 0; k < 8; ++k) ov[k] = f2bf(qint((w[base + k] * xv[k]) * rs, alpha));
  u16* orow = out + (size_t)row * C_DIM + base;
#pragma unroll
  for (int k = 0; k < 2; ++k) {
    ushort4 u;
    u.x = ov[k * 4]; u.y = ov[k * 4 + 1]; u.z = ov[k * 4 + 2]; u.w = ov[k * 4 + 3];
    *reinterpret_cast<ushort4*>(orow + k * 4) = u;
  }
}

// ---------------------------------------------------------------------------
// Multi-term bf16 MFMA GEMM, double-buffered, in-register B-split from fp32.
//   C[m,n] = sum_k A_terms . (Bhi + Blo)[n,k],  Bhi=trunc16(B), Blo=RNE(B-Bhi)
// MODE 2: (A0,Bhi)+(A0,Blo).   MODE 3: (A0,Bhi)+(A1,Bhi)+(A0,Blo).
// LDS/buffer: A0 [128][32]bf16 (8K) | (MODE3) A1 (8K) | Bf32 [128][32] (16K,
// XOR-swizzled (row&7)<<4 via pre-permuted global source).
// EPI 0: Cf = aux + acc;  EPI 1: quant levels;  EPI 2: split planes;
// EPI 3: gu = silu(g)*acc -> split planes (in place).
// ---------------------------------------------------------------------------
template <int MODE, int EPI>
__global__ __launch_bounds__(256) void gemm_mfma(
    const u16* __restrict__ A0, const u16* __restrict__ A1,
    const float* __restrict__ Bf,
    float* __restrict__ Cf, u16* __restrict__ Cq, const float* __restrict__ auxf,
    u16* __restrict__ p_hi, u16* __restrict__ p_lo,
    const float* __restrict__ sA_p, const float* __restrict__ aQ_p,
    int M, int N, int K) {
  constexpr int BUFB = (MODE == 2) ? 24576 : 32768;
  constexpr int BOFF = (MODE == 2) ? 8192 : 16384;
  __shared__ __align__(16) char lds[2 * BUFB];

  const int tid = threadIdx.x;
  const int nwg = gridDim.x * gridDim.y;
  const int wg = blockIdx.y * gridDim.x + blockIdx.x;
  const int swz = (wg & 7) * (nwg >> 3) + (wg >> 3);
  const int bx = swz % gridDim.x, by = swz / gridDim.x;
  const int row0 = by * 128, col0 = bx * 128;

  const int w = tid >> 6, lane = tid & 63;
  const int wr = w >> 1, wc = w & 1;
  const int fr = lane & 15, gq = lane >> 4;

  // A staging geometry: chunk c = w*128+lane (+64)
  const int c0 = w * 128 + lane;
  const int r_a = c0 >> 2;
  const int s_a = (c0 & 3) * 8;
  // B staging geometry: 1024 chunks of 16B; chunk = it*256+tid
  const int rB = tid >> 3;          // row within 32-row group
  const int sB0 = tid & 7;          // dest 16B slot

  char* cu = lds;
  char* nx = lds + BUFB;

  auto stage = [&](char* base, int kt) {
    {
      const u16* g0 = A0 + (size_t)(row0 + r_a) * K + kt + s_a;
      const u16* g1 = A0 + (size_t)(row0 + r_a + 16) * K + kt + s_a;
      llds16(g0, base + (w * 128) * 16);
      llds16(g1, base + (w * 128 + 64) * 16);
    }
    if constexpr (MODE == 3) {
      const u16* g0 = A1 + (size_t)(row0 + r_a) * K + kt + s_a;
      const u16* g1 = A1 + (size_t)(row0 + r_a + 16) * K + kt + s_a;
      llds16(g0, base + 8192 + (w * 128) * 16);
      llds16(g1, base + 8192 + (w * 128 + 64) * 16);
    }
#pragma unroll
    for (int it = 0; it < 4; ++it) {
      const int rowB = it * 32 + rB;
      const int slot = sB0 ^ (rowB & 7);   // inverse of read-side XOR swizzle
      const float* gp = Bf + (size_t)(col0 + rowB) * K + kt + slot * 4;
      llds16(gp, base + BOFF + it * 4096 + w * 1024);
    }
  };

  f32x4 acc[4][4];
  const f32x4 zero = {0.f, 0.f, 0.f, 0.f};
#pragma unroll
  for (int m = 0; m < 4; ++m)
#pragma unroll
    for (int n = 0; n < 4; ++n) acc[m][n] = zero;

  stage(cu, 0);
  __syncthreads();

  for (int kt = 0;; kt += 32) {
    const bool more = (kt + 32 < K);
    if (more) stage(nx, kt + 32);   // prefetch overlaps this tile's compute

    const char* bufA = cu;
    const char* bufB = cu + BOFF;
    bf16x8 a0f[4], bhf[4], blf[4];
#pragma unroll
    for (int m = 0; m < 4; ++m)
      a0f[m] = *reinterpret_cast<const bf16x8*>(
          bufA + (wr * 64 + m * 16 + fr) * 64 + gq * 16);
#pragma unroll
    for (int n = 0; n < 4; ++n) {
      const int rowB = wc * 64 + n * 16 + fr;
      const int bb = rowB * 128 + gq * 32;
      const int sw = (rowB & 7) << 4;
      f32x4 e0 = *reinterpret_cast<const f32x4*>(bufB + (bb ^ sw));
      f32x4 e1 = *reinterpret_cast<const f32x4*>(bufB + ((bb + 16) ^ sw));
      float e[8] = {e0[0], e0[1], e0[2], e0[3], e1[0], e1[1], e1[2], e1[3]};
      u32 hp[4], lp[4];
#pragma unroll
      for (int p = 0; p < 4; ++p) {
        const u32 u0 = __builtin_bit_cast(u32, e[2 * p]);
        const u32 u1 = __builtin_bit_cast(u32, e[2 * p + 1]);
        hp[p] = (u1 & 0xffff0000u) | (u0 >> 16);         // trunc-bf16 hi pair
        const float l0 = e[2 * p]     - __builtin_bit_cast(float, u0 & 0xffff0000u);
        const float l1 = e[2 * p + 1] - __builtin_bit_cast(float, u1 & 0xffff0000u);
        lp[p] = cvtpk_bf16(l0, l1);                      // RNE lo pair
      }
      u32x4 hv = {hp[0], hp[1], hp[2], hp[3]};
      u32x4 lv = {lp[0], lp[1], lp[2], lp[3]};
      bhf[n] = __builtin_bit_cast(bf16x8, hv);
      blf[n] = __builtin_bit_cast(bf16x8, lv);
    }
    if constexpr (MODE == 2) {
#pragma unroll
      for (int m = 0; m < 4; ++m)
#pragma unroll
        for (int n = 0; n < 4; ++n) {
          acc[m][n] = __builtin_amdgcn_mfma_f32_16x16x32_bf16(a0f[m], bhf[n], acc[m][n], 0, 0, 0);
          acc[m][n] = __builtin_amdgcn_mfma_f32_16x16x32_bf16(a0f[m], blf[n], acc[m][n], 0, 0, 0);
        }
    } else {
      bf16x8 a1f[4];
#pragma unroll
      for (int m = 0; m < 4; ++m)
        a1f[m] = *reinterpret_cast<const bf16x8*>(
            cu + 8192 + (wr * 64 + m * 16 + fr) * 64 + gq * 16);
#pragma unroll
      for (int m = 0; m < 4; ++m)
#pragma unroll
        for (int n = 0; n < 4; ++n) {
          acc[m][n] = __builtin_amdgcn_mfma_f32_16x16x32_bf16(a0f[m], bhf[n], acc[m][n], 0, 0, 0);
          acc[m][n] = __builtin_amdgcn_mfma_f32_16x16x32_bf16(a1f[m], bhf[n], acc[m][n], 0, 0, 0);
          acc[m][n] = __builtin_amdgcn_mfma_f32_16x16x32_bf16(a0f[m], blf[n], acc[m][n], 0, 0, 0);
        }
    }
    if (!more) break;
    __syncthreads();   // drains prefetch vmcnt + this tile's readers
    char* t = cu; cu = nx; nx = t;
  }

  float sA = 1.0f, aQ = 1.0f;
  if constexpr (EPI == 1) { sA = (*sA_p) * (1.0f / 63.0f); aQ = *aQ_p; }
  if constexpr (EPI == 2 || EPI == 3) { sA = (*sA_p) * (1.0f / 63.0f); }
#pragma unroll
  for (int m = 0; m < 4; ++m)
#pragma unroll
    for (int n = 0; n < 4; ++n) {
      const int gcol = col0 + wc * 64 + n * 16 + fr;
#pragma unroll
      for (int j = 0; j < 4; ++j) {
        const int grow = row0 + wr * 64 + m * 16 + (lane >> 4) * 4 + j;
        const size_t idx = (size_t)grow * N + gcol;
        const float v = acc[m][n][j];
        if constexpr (EPI == 0) {
          Cf[idx] = auxf[idx] + v;
        } else if constexpr (EPI == 1) {
          float t = v * sA;
          float xd = fminf(fmaxf(t, 0.0f) / aQ, 1.0f);
          Cq[idx] = f2bf(rintf(xd * 63.0f));
        } else if constexpr (EPI == 2) {
          float t = v * sA;
          u16 h = f2bf(t);
          p_hi[idx] = h;
          p_lo[idx] = f2bf(t - bf2f(h));
        } else if constexpr (EPI == 3) {
          float gg = bf2f(p_hi[idx]) + bf2f(p_lo[idx]);
          float u = v * sA;
          float gu = (gg / (1.0f + expf(-gg))) * u;
          u16 h = f2bf(gu);
          p_hi[idx] = h;
          p_lo[idx] = f2bf(gu - bf2f(h));
        }
      }
    }
}

// ---------------------------------------------------------------------------
// V pre-transpose: vt[g][hs][t] = qkv[t][(g*6+5)*64 + hs]  (bf16 levels)
// ---------------------------------------------------------------------------
__global__ __launch_bounds__(256) void v_transpose(const u16* __restrict__ qkv,
                                                   u16* __restrict__ vt) {
  const int tb = blockIdx.x, g = blockIdx.y;
  const int vcol = (g * 6 + 5) * 64;
  __shared__ u16 t[64][72];
  const int tid = threadIdx.x;
#pragma unroll
  for (int i = 0; i < 2; ++i) {
    const int ch = i * 256 + tid;
    const int row = ch >> 3, c8 = (ch & 7) * 8;
    bf16x8 v = *reinterpret_cast<const bf16x8*>(
        qkv + (size_t)(tb * 64 + row) * QKV_DIM + vcol + c8);
#pragma unroll
    for (int j = 0; j < 8; ++j) t[c8 + j][row] = (u16)v[j];
  }
  __syncthreads();
#pragma unroll
  for (int i = 0; i < 2; ++i) {
    const int ch = i * 256 + tid;
    const int hs = ch >> 3, t8 = (ch & 7) * 8;
    ushort4 a, b;
    a.x = t[hs][t8];     a.y = t[hs][t8 + 1]; a.z = t[hs][t8 + 2]; a.w = t[hs][t8 + 3];
    b.x = t[hs][t8 + 4]; b.y = t[hs][t8 + 5]; b.z = t[hs][t8 + 6]; b.w = t[hs][t8 + 7];
    u16* dst = vt + (size_t)(g * 64 + hs) * T_SEQ + tb * 64 + t8;
    *reinterpret_cast<ushort4*>(dst) = a;
    *reinterpret_cast<ushort4*>(dst + 4) = b;
  }
}

// ---------------------------------------------------------------------------
// Fused MFMA attention (unchanged from round 5, verified).
// ---------------------------------------------------------------------------
__global__ __launch_bounds__(256) void attn_fused(const u16* __restrict__ qkv,
                                                  const u16* __restrict__ vt,
                                                  u16* __restrict__ y_hi,
                                                  u16* __restrict__ y_lo,
                                                  const float* __restrict__ aq_p,
                                                  const float* __restrict__ asm_p) {
  const int c = blockIdx.x;
  const int chi = c >> 8, mid = (c >> 4) & 15, clo = c & 15;
  const int h = mid + (chi << 4);
  const int qb = chi ? (15 - clo) : clo;
  const int g = h >> 2, s = h & 3;
  const int q_col = (g * 6 + s) * 64;
  const int k_col = (g * 6 + 4) * 64;

  __shared__ __align__(16) char lds_raw[49152];
  u16* Ks  = (u16*)(lds_raw + 16384);
  u16* Vts = (u16*)(lds_raw + 24576);

  const int tid = threadIdx.x;
  const int w = tid >> 6, lane = tid & 63;
  const int fr = lane & 15, gg = lane >> 4;
  char* myW = lds_raw + 32768 + w * 4096;

  const float sq = (*aq_p) * (1.0f / 63.0f);
  const float scale2 = sq * sq * 0.125f * LOG2E;
  const float alpha_sm = *asm_p;
  const float inv_a63 = 63.0f / alpha_sm;
  const float scale_y = (alpha_sm * (1.0f / 63.0f)) * sq;
  const int nkt = 2 * qb + 2;

#pragma unroll
  for (int i = 0; i < 4; ++i) {
    const int cb = (w * 4 + i) * 64;
    const int ch = cb + lane;
    const int row = ch >> 3;
    const int sb = ((ch & 7) * 16) ^ ((row & 7) << 4);
    llds16(qkv + (size_t)(qb * 128 + row) * QKV_DIM + q_col + (sb >> 1),
           lds_raw + cb * 16);
  }
  __syncthreads();
  bf16x8 qf[2][2];
#pragma unroll
  for (int nq = 0; nq < 2; ++nq)
#pragma unroll
    for (int ks = 0; ks < 2; ++ks) {
      const int qr = w * 32 + nq * 16 + fr;
      qf[nq][ks] = *reinterpret_cast<const bf16x8*>(
          lds_raw + ((qr * 128 + ks * 64 + gg * 16) ^ ((qr & 7) << 4)));
    }

  float m_run[2] = {-INFINITY, -INFINITY};
  float l_run[2] = {0.0f, 0.0f};

  for (int kt = 0; kt < nkt; ++kt) {
    __syncthreads();
#pragma unroll
    for (int i = 0; i < 2; ++i) {
      const int cb = (w * 2 + i) * 64;
      const int ch = cb + lane;
      const int row = ch >> 3;
      const int sb = ((ch & 7) * 16) ^ ((row & 7) << 4);
      llds16(qkv + (size_t)(kt * 64 + row) * QKV_DIM + k_col + (sb >> 1),
             (char*)Ks + cb * 16);
    }
    __syncthreads();
    f32x4 sac[4][2];
    const f32x4 zero = {0.f, 0.f, 0.f, 0.f};
#pragma unroll
    for (int mk = 0; mk < 4; ++mk)
#pragma unroll
      for (int nq = 0; nq < 2; ++nq) sac[mk][nq] = zero;
#pragma unroll
    for (int ks = 0; ks < 2; ++ks)
#pragma unroll
      for (int mk = 0; mk < 4; ++mk) {
        const int kr = mk * 16 + fr;
        bf16x8 kf = *reinterpret_cast<const bf16x8*>(
            (char*)Ks + ((kr * 128 + ks * 64 + gg * 16) ^ ((kr & 7) << 4)));
#pragma unroll
        for (int nq = 0; nq < 2; ++nq)
          sac[mk][nq] = __builtin_amdgcn_mfma_f32_16x16x32_bf16(kf, qf[nq][ks], sac[mk][nq], 0, 0, 0);
      }
    const bool edge = (kt >= 2 * qb);
#pragma unroll
    for (int nq = 0; nq < 2; ++nq) {
      const int qglob = qb * 128 + w * 32 + nq * 16 + fr;
      float tv[16];
#pragma unroll
      for (int mk = 0; mk < 4; ++mk)
#pragma unroll
        for (int jj = 0; jj < 4; ++jj) {
          float t = sac[mk][nq][jj] * scale2;
          if (edge && (kt * 64 + mk * 16 + gg * 4 + jj > qglob)) t = -INFINITY;
          tv[mk * 4 + jj] = t;
        }
      float vm = tv[0];
#pragma unroll
      for (int i = 1; i < 16; ++i) vm = fmaxf(vm, tv[i]);
      vm = fmaxf(vm, __shfl_xor(vm, 16));
      vm = fmaxf(vm, __shfl_xor(vm, 32));
      const float mn = fmaxf(m_run[nq], vm);
      float p = 0.0f;
#pragma unroll
      for (int i = 0; i < 16; ++i) p += exp2_hw(tv[i] - mn);
      p += __shfl_xor(p, 16);
      p += __shfl_xor(p, 32);
      l_run[nq] = l_run[nq] * exp2_hw(m_run[nq] - mn) + p;
      m_run[nq] = mn;
    }
  }

  const float linv[2] = {1.0f / l_run[0], 1.0f / l_run[1]};
  f32x4 oac[4][2];
  {
    const f32x4 zero = {0.f, 0.f, 0.f, 0.f};
#pragma unroll
    for (int mh = 0; mh < 4; ++mh)
#pragma unroll
      for (int nq = 0; nq < 2; ++nq) oac[mh][nq] = zero;
  }

  for (int kt = 0; kt < nkt; ++kt) {
    __syncthreads();
#pragma unroll
    for (int i = 0; i < 2; ++i) {
      const int cb = (w * 2 + i) * 64;
      const int ch = cb + lane;
      const int row = ch >> 3;
      const int sb = ((ch & 7) * 16) ^ ((row & 7) << 4);
      llds16(qkv + (size_t)(kt * 64 + row) * QKV_DIM + k_col + (sb >> 1),
             (char*)Ks + cb * 16);
      llds16(vt + (size_t)(g * 64 + row) * T_SEQ + kt * 64 + (sb >> 1),
             (char*)Vts + cb * 16);
    }
    __syncthreads();
    f32x4 sac[4][2];
    const f32x4 zero = {0.f, 0.f, 0.f, 0.f};
#pragma unroll
    for (int mk = 0; mk < 4; ++mk)
#pragma unroll
      for (int nq = 0; nq < 2; ++nq) sac[mk][nq] = zero;
#pragma unroll
    for (int ks = 0; ks < 2; ++ks)
#pragma unroll
      for (int mk = 0; mk < 4; ++mk) {
        const int kr = mk * 16 + fr;
        bf16x8 kf = *reinterpret_cast<const bf16x8*>(
            (char*)Ks + ((kr * 128 + ks * 64 + gg * 16) ^ ((kr & 7) << 4)));
#pragma unroll
        for (int nq = 0; nq < 2; ++nq)
          sac[mk][nq] = __builtin_amdgcn_mfma_f32_16x16x32_bf16(kf, qf[nq][ks], sac[mk][nq], 0, 0, 0);
      }
    const bool edge = (kt >= 2 * qb);
#pragma unroll
    for (int nq = 0; nq < 2; ++nq) {
      const int qglob = qb * 128 + w * 32 + nq * 16 + fr;
      const int qloc = nq * 16 + fr;
      const float mr = m_run[nq];
      const float cw = linv[nq] * inv_a63;
#pragma unroll
      for (int mk = 0; mk < 4; ++mk) {
        float lv[4];
#pragma unroll
        for (int jj = 0; jj < 4; ++jj) {
          float t = sac[mk][nq][jj] * scale2;
          if (edge && (kt * 64 + mk * 16 + gg * 4 + jj > qglob)) t = -INFINITY;
          lv[jj] = rintf(fminf(exp2_hw(t - mr) * cw, 63.0f));
        }
        const u32 pk0 = cvtpk_bf16(lv[0], lv[1]);
        const u32 pk1 = cvtpk_bf16(lv[2], lv[3]);
        const int b0 = (qloc * 128 + (mk * 16 + gg * 4) * 2) ^ ((qloc & 7) << 4);
        *reinterpret_cast<u32*>(myW + b0) = pk0;
        *reinterpret_cast<u32*>(myW + b0 + 4) = pk1;
      }
    }
#pragma unroll
    for (int ks = 0; ks < 2; ++ks) {
      bf16x8 wf[2];
#pragma unroll
      for (int nq = 0; nq < 2; ++nq) {
        const int qloc = nq * 16 + fr;
        wf[nq] = *reinterpret_cast<const bf16x8*>(
            myW + ((qloc * 128 + ks * 64 + gg * 16) ^ ((qloc & 7) << 4)));
      }
#pragma unroll
      for (int mh = 0; mh < 4; ++mh) {
        const int hr = mh * 16 + fr;
        bf16x8 vf = *reinterpret_cast<const bf16x8*>(
            (char*)Vts + ((hr * 128 + ks * 64 + gg * 16) ^ ((hr & 7) << 4)));
#pragma unroll
        for (int nq = 0; nq < 2; ++nq)
          oac[mh][nq] = __builtin_amdgcn_mfma_f32_16x16x32_bf16(vf, wf[nq], oac[mh][nq], 0, 0, 0);
      }
    }
  }

  __syncthreads();
  float* osc = (float*)(lds_raw + w * 8192);
#pragma unroll
  for (int mh = 0; mh < 4; ++mh)
#pragma unroll
    for (int nq = 0; nq < 2; ++nq) {
      const int qloc = nq * 16 + fr;
#pragma unroll
      for (int jj = 0; jj < 4; ++jj) {
        const int hs = mh * 16 + gg * 4 + jj;
        *reinterpret_cast<float*>(
            (char*)osc + ((qloc * 256 + hs * 4) ^ ((qloc & 7) << 4))) =
            oac[mh][nq][jj] * scale_y;
      }
    }
  __syncthreads();
  const int qp = lane >> 1, hf = lane & 1;
  const int qrow = qb * 128 + w * 32 + qp;
  u16* dh = y_hi + (size_t)qrow * C_DIM + h * 64 + hf * 32;
  u16* dl = y_lo + (size_t)qrow * C_DIM + h * 64 + hf * 32;
#pragma unroll
  for (int u = 0; u < 8; ++u) {
    f32x4 v = *reinterpret_cast<const f32x4*>(
        (char*)osc + ((qp * 256 + hf * 128 + u * 16) ^ ((qp & 7) << 4)));
    ushort4 hh, ll;
    u16 t0 = f2bf(v[0]); hh.x = t0; ll.x = f2bf(v[0] - bf2f(t0));
    u16 t1 = f2bf(v[1]); hh.y = t1; ll.y = f2bf(v[1] - bf2f(t1));
    u16 t2 = f2bf(v[2]); hh.z = t2; ll.z = f2bf(v[2] - bf2f(t2));
    u16 t3 = f2bf(v[3]); hh.w = t3; ll.w = f2bf(v[3] - bf2f(t3));
    *reinterpret_cast<ushort4*>(dh + u * 4) = hh;
    *reinterpret_cast<ushort4*>(dl + u * 4) = ll;
  }
}

// ---------------------------------------------------------------------------
extern "C" void kernel_launch(void* const* d_in, const int* in_sizes, int n_in,
                              void* d_out, int out_size, void* d_ws, size_t ws_size,
                              hipStream_t stream) {
  (void)in_sizes; (void)n_in; (void)out_size; (void)ws_size;
  const float* x      = (const float*)d_in[0];
  const float* w1     = (const float*)d_in[1];
  const float* w2     = (const float*)d_in[2];
  const float* a1     = (const float*)d_in[3];
  const float* a2     = (const float*)d_in[4];
  const float* aq     = (const float*)d_in[5];
  const float* a_sm   = (const float*)d_in[6];
  const float* attn_w = (const float*)d_in[7];
  const float* proj_w = (const float*)d_in[8];
  const float* fc1_w  = (const float*)d_in[9];
  const float* fc2_w  = (const float*)d_in[10];
  const float* mlp_w  = (const float*)d_in[11];
  float* out = (float*)d_out;

  // Workspace (bytes), total 54,525,952 (52 MiB):
  //   [0, 8388608)       nb: n1/n2 integer levels (bf16)
  //   R = [8388608, ...) phase A: qkv_i(12.6M) | y_hi(8.4M) | y_lo(8.4M) | vt(2M)
  //                      phase B (after proj): ghi(23.1M) | glo(23.1M)
  char* ws = (char*)d_ws;
  u16* nb    = (u16*)ws;
  char* R    = ws + 8388608;
  u16* qkv_i = (u16*)R;
  u16* y_hi  = (u16*)(R + 12582912);
  u16* y_lo  = (u16*)(R + 20971520);
  u16* vt    = (u16*)(R + 29360128);
  u16* ghi   = (u16*)R;
  u16* glo   = (u16*)(R + 23068672);

  // 1) n1 levels
  rmsnorm_quant_int<<<T_SEQ, 256, 0, stream>>>(x, w1, a1, nb);
  // 2) qkv = quant levels of (n1 @ attn_w^T)   (fp32 weights, in-kernel split)
  gemm_mfma<2, 1><<<dim3(QKV_DIM / 128, T_SEQ / 128), 256, 0, stream>>>(
      nb, nullptr, attn_w, nullptr, qkv_i, nullptr, nullptr, nullptr,
      a1, aq, T_SEQ, QKV_DIM, C_DIM);
  // 3) attention (MFMA)
  v_transpose<<<dim3(32, 8), 256, 0, stream>>>(qkv_i, vt);
  attn_fused<<<512, 256, 0, stream>>>(qkv_i, vt, y_hi, y_lo, aq, a_sm);
  // 4) x2 = x + y @ proj_w^T
  gemm_mfma<3, 0><<<dim3(C_DIM / 128, T_SEQ / 128), 256, 0, stream>>>(
      y_hi, y_lo, proj_w, out, nullptr, x, nullptr, nullptr,
      nullptr, nullptr, T_SEQ, C_DIM, C_DIM);
  // 5) n2 levels
  rmsnorm_quant_int<<<T_SEQ, 256, 0, stream>>>(out, w2, a2, nb);
  // 6) g = n2 @ fc1_w^T  (full FF, split planes)
  gemm_mfma<2, 2><<<dim3(FF_DIM / 128, T_SEQ / 128), 256, 0, stream>>>(
      nb, nullptr, fc1_w, nullptr, nullptr, nullptr, ghi, glo,
      a2, nullptr, T_SEQ, FF_DIM, C_DIM);
  // 7) gu = silu(g) * (n2 @ fc2_w^T)  (in place over g planes)
  gemm_mfma<2, 3><<<dim3(FF_DIM / 128, T_SEQ / 128), 256, 0, stream>>>(
      nb, nullptr, fc2_w, nullptr, nullptr, nullptr, ghi, glo,
      a2, nullptr, T_SEQ, FF_DIM, C_DIM);
  // 8) out = x2 + gu @ mlp_proj_w^T   (K = FF)
  gemm_mfma<3, 0><<<dim3(C_DIM / 128, T_SEQ / 128), 256, 0, stream>>>(
      ghi, glo, mlp_w, out, nullptr, out, nullptr, nullptr,
      nullptr, nullptr, T_SEQ, C_DIM, FF_DIM);
}